// Round 10
// baseline (788.944 us; speedup 1.0000x reference)
//
#include <hip/hip_runtime.h>
#include <hip/hip_bf16.h>
#include <stdint.h>

typedef __bf16 bf16;
typedef __bf16 bf16x8 __attribute__((ext_vector_type(8)));
typedef float  f32x4  __attribute__((ext_vector_type(4)));
typedef float  f32x16 __attribute__((ext_vector_type(16)));

#define MFMA16(a,b,c) __builtin_amdgcn_mfma_f32_16x16x32_bf16(a,b,c,0,0,0)
#define MFMA32(a,b,c) __builtin_amdgcn_mfma_f32_32x32x16_bf16(a,b,c,0,0,0)

__device__ __forceinline__ f32x4 zero4() { f32x4 z; z[0]=0.f; z[1]=0.f; z[2]=0.f; z[3]=0.f; return z; }

__device__ __forceinline__ uint32_t packbf(float lo, float hi) {
    union { bf16 b[2]; uint32_t u; } t;
    t.b[0] = (bf16)lo; t.b[1] = (bf16)hi;
    return t.u;
}
__device__ __forceinline__ bf16x8 frag_from_words(uint32_t w0, uint32_t w1, uint32_t w2, uint32_t w3) {
    union { uint32_t u[4]; bf16x8 v; } t;
    t.u[0] = w0; t.u[1] = w1; t.u[2] = w2; t.u[3] = w3;
    return t.v;
}
__device__ __forceinline__ float uf(uint32_t u) {
    union { uint32_t u; float f; } t; t.u = u; return t.f;
}
// fast GELU (tanh form, max err ~3e-3)
__device__ __forceinline__ float gelu_f(float u) {
    float u2 = u * u;
    float y  = u * (0.7978845608f + 0.0356774081f * u2);
    float e  = __expf(2.0f * y);
    float t  = 1.0f - 2.0f / (e + 1.0f);
    return 0.5f * u * (1.0f + t);
}

// ---------------------------------------------------------------------------
// prep: weights f32 -> bf16 [n][k]; bias matrix natural: bN[h][q][k]
// ws layout (bytes):
//   0      : wqkvT  [384][128] bf16   (98304)
//   98304  : wprojT [128][128] bf16   (32768)
//   131072 : wfc1T  [512][128] bf16   (131072)
//   262144 : wfc2T  [128][512] bf16   (131072)
//   393216 : bN     [8][64][64] f32   (131072)
//   524288 : win2tm [4096][64][128] f32 (134217728)   [split path only]
// ---------------------------------------------------------------------------
__global__ __launch_bounds__(512) void prep_kernel(
    const float* __restrict__ wqkv, const float* __restrict__ wproj,
    const float* __restrict__ wfc1, const float* __restrict__ wfc2,
    const float* __restrict__ btab, const int* __restrict__ relidx,
    bf16* __restrict__ wqkvT, bf16* __restrict__ wprojT,
    bf16* __restrict__ wfc1T, bf16* __restrict__ wfc2T,
    float* __restrict__ bN)
{
    int i = blockIdx.x * 512 + threadIdx.x;
    if (i < 49152) { int n = i >> 7, k = i & 127; wqkvT[i] = (bf16)wqkv[k*384 + n]; return; }
    i -= 49152;
    if (i < 16384) { int n = i >> 7, k = i & 127; wprojT[i] = (bf16)wproj[k*128 + n]; return; }
    i -= 16384;
    if (i < 65536) { int n = i >> 7, k = i & 127; wfc1T[i] = (bf16)wfc1[k*512 + n]; return; }
    i -= 65536;
    if (i < 65536) { int n = i >> 9, k = i & 511; wfc2T[i] = (bf16)wfc2[k*128 + n]; return; }
    i -= 65536;
    if (i < 32768) { int h = i >> 12, q = (i >> 6) & 63, k = i & 63;
                     bN[i] = btab[relidx[q*64 + k]*8 + h]; }
}

// ---------------------------------------------------------------------------
// kernel1: x -> LN1 -> QKV -> attention -> proj + residual -> win2 (token-major f32)
// LDS 49152 = A(x->vT) | B(h->q) | C(k->o); winp residual regs. 7 barriers.
// ---------------------------------------------------------------------------
__global__ __launch_bounds__(512, 4) void swin_attn(
    const float* __restrict__ x,
    const float* __restrict__ ln1_g, const float* __restrict__ ln1_b,
    const float* __restrict__ b_qkv, const float* __restrict__ b_proj,
    const bf16* __restrict__ wqkvT, const bf16* __restrict__ wprojT,
    const float* __restrict__ bN,
    float* __restrict__ win2tm)
{
    __shared__ __align__(16) char sm[49152];

    const int tid  = threadIdx.x;
    const int lane = tid & 63;
    const int wv   = tid >> 6;
    const int l15  = lane & 15;
    const int l4   = (lane >> 4) & 3;
    const int l31  = lane & 31;
    const int hi   = lane >> 5;
    const int fmt  = wv >> 1;
    const int fn0  = (wv & 1) * 64;

    const int wid = ((blockIdx.x & 7) << 9) | (blockIdx.x >> 3);
    const int bb  = wid >> 10;
    const int hw  = (wid >> 5) & 31;
    const int wwi = wid & 31;
    const size_t base = (size_t)bb * 8388608 + (size_t)hw * 2048 + (size_t)wwi * 8;
    const float* xw = x + base;

    // P1: stage x window as bf16 [tok][c] into A
#pragma unroll
    for (int it = 0; it < 4; ++it) {
        int idx = it*512 + tid;
        int c = idx >> 4, t2 = idx & 15;
        int row = t2 >> 1, col0 = (t2 & 1) * 4;
        f32x4 v = *(const f32x4*)(xw + (size_t)c*65536 + row*256 + col0);
#pragma unroll
        for (int e = 0; e < 4; ++e) {
            int t = row*8 + col0 + e;
            *(bf16*)(sm + t*256 + ((2*c) ^ ((t&7)<<4))) = (bf16)v[e];
        }
    }
    __syncthreads();   // B1

    // P1.5: residual -> 8 packed-bf16 regs
    uint32_t winp[2][4];
#pragma unroll
    for (int r = 0; r < 4; ++r) {
        int tok = fmt*16 + l4*4 + r;
        int swz = (tok & 7) << 4;
        const char* rowp = sm + tok*256;
        uint32_t c0 = *(const uint16_t*)(rowp + ((2*(fn0 +  0 + l15)) ^ swz));
        uint32_t c1 = *(const uint16_t*)(rowp + ((2*(fn0 + 16 + l15)) ^ swz));
        uint32_t c2 = *(const uint16_t*)(rowp + ((2*(fn0 + 32 + l15)) ^ swz));
        uint32_t c3 = *(const uint16_t*)(rowp + ((2*(fn0 + 48 + l15)) ^ swz));
        winp[0][r] = c0 | (c1 << 16);
        winp[1][r] = c2 | (c3 << 16);
    }

    // P2: LN1 (reads A) -> h in B
    {
        const int t = tid >> 3, p = tid & 7;
        const int swz = (t & 7) << 4;
        float vv[16];
        float s = 0.f, s2 = 0.f;
#pragma unroll
        for (int hlf = 0; hlf < 2; ++hlf) {
            bf16x8 xv = *(const bf16x8*)(sm + t*256 + ((p*32 + hlf*16) ^ swz));
#pragma unroll
            for (int e = 0; e < 8; ++e) { float f = (float)xv[e]; vv[hlf*8+e] = f; s += f; s2 += f*f; }
        }
#pragma unroll
        for (int m = 1; m < 8; m <<= 1) { s += __shfl_xor(s, m, 64); s2 += __shfl_xor(s2, m, 64); }
        const float mean = s * 0.0078125f;
        const float rs = rsqrtf(s2 * 0.0078125f - mean*mean + 1e-5f);
#pragma unroll
        for (int hlf = 0; hlf < 2; ++hlf) {
            bf16x8 hv;
#pragma unroll
            for (int e = 0; e < 8; ++e) {
                int c = p*16 + hlf*8 + e;
                hv[e] = (bf16)((vv[hlf*8+e] - mean) * rs * ln1_g[c] + ln1_b[c]);
            }
            *(bf16x8*)(sm + 16384 + t*256 + ((p*32 + hlf*16) ^ swz)) = hv;
        }
    }
    __syncthreads();   // B2 — A free for vT

    // P3: QKV GEMM, two mt-half-passes (q->B, k->C, vT->A)
    {
        const float SCALE = 0.35355339059327373f;
        const int nq0 = wv * 32;
        const int nv  = 256 + wv*16 + l15;
        const float bb0 = b_qkv[nq0 + l15];
        const float bb1 = b_qkv[nq0 + 16 + l15];
        const float bbv = b_qkv[nv];
        const bool isq = (nq0 < 128);
        char* rb = isq ? (sm + 16384) : (sm + 32768);
        const float sc = isq ? SCALE : 1.0f;
        const int c0 = (nq0 & 127) + l15;
        const int c1 = ((nq0 + 16) & 127) + l15;
#pragma unroll
        for (int half = 0; half < 2; ++half) {
            f32x4 a0[2], a1[2], avh[2];
#pragma unroll
            for (int m2 = 0; m2 < 2; ++m2) { a0[m2] = zero4(); a1[m2] = zero4(); avh[m2] = zero4(); }
#pragma unroll
            for (int ks = 0; ks < 4; ++ks) {
                bf16x8 bq0 = *(const bf16x8*)(wqkvT + (nq0      + l15)*128 + ks*32 + l4*8);
                bf16x8 bq1 = *(const bf16x8*)(wqkvT + (nq0 + 16 + l15)*128 + ks*32 + l4*8);
                bf16x8 bv  = *(const bf16x8*)(wqkvT + nv*128 + ks*32 + l4*8);
#pragma unroll
                for (int m2 = 0; m2 < 2; ++m2) {
                    int tok = half*32 + m2*16 + l15;
                    bf16x8 afr = *(const bf16x8*)(sm + 16384 + tok*256 + ((ks*64 + l4*16) ^ ((tok&7)<<4)));
                    a0[m2]  = MFMA16(afr, bq0, a0[m2]);
                    a1[m2]  = MFMA16(afr, bq1, a1[m2]);
                    avh[m2] = MFMA16(afr, bv,  avh[m2]);
                }
            }
            __syncthreads();   // B3a / B3b
#pragma unroll
            for (int m2 = 0; m2 < 2; ++m2)
#pragma unroll
                for (int r = 0; r < 4; ++r) {
                    int tok = half*32 + m2*16 + l4*4 + r;
                    int swz = (tok & 7) << 4;
                    *(bf16*)(rb + tok*256 + ((2*c0) ^ swz)) = (bf16)((a0[m2][r] + bb0) * sc);
                    *(bf16*)(rb + tok*256 + ((2*c1) ^ swz)) = (bf16)((a1[m2][r] + bb1) * sc);
                }
            {
                int d = l15;
                char* vb = sm + wv*2048 + d*128;
                int sz = (d & 7) << 4;
#pragma unroll
                for (int m2 = 0; m2 < 2; ++m2) {
                    int t0 = half*32 + m2*16 + l4*4;
                    *(uint32_t*)(vb + ((2*t0)     ^ sz)) = packbf(avh[m2][0]+bbv, avh[m2][1]+bbv);
                    *(uint32_t*)(vb + ((2*t0 + 4) ^ sz)) = packbf(avh[m2][2]+bbv, avh[m2][3]+bbv);
                }
            }
        }
    }
    __syncthreads();   // B3

    // P4: attention (wave = head)
    {
        bf16x8 kf[2];
#pragma unroll
        for (int tk = 0; tk < 2; ++tk) {
            int tok = tk*32 + l31;
            kf[tk] = *(const bf16x8*)(sm + 32768 + tok*256 + ((wv*32 + hi*16) ^ ((tok&7)<<4)));
        }
        __syncthreads();   // B4 — C free for o
#pragma unroll
        for (int tq = 0; tq < 2; ++tq) {
            int q = tq*32 + l31;
            bf16x8 qf = *(const bf16x8*)(sm + 16384 + q*256 + ((wv*32 + hi*16) ^ ((q&7)<<4)));
            const float* bq = bN + wv*4096 + q*64 + 4*hi;
            float ss, ri;
            uint32_t own[16];
            {
                f32x16 s0, s1;
#pragma unroll
                for (int g4 = 0; g4 < 4; ++g4) {
                    f32x4 b0 = *(const f32x4*)(bq + g4*8);
                    f32x4 b1 = *(const f32x4*)(bq + 32 + g4*8);
#pragma unroll
                    for (int e = 0; e < 4; ++e) { s0[g4*4+e] = b0[e]; s1[g4*4+e] = b1[e]; }
                }
                s0 = MFMA32(kf[0], qf, s0);
                s1 = MFMA32(kf[1], qf, s1);
                ss = 0.f;
#pragma unroll
                for (int r = 0; r < 16; ++r) {
                    s0[r] = __expf(s0[r]);
                    s1[r] = __expf(s1[r]);
                    ss += s0[r] + s1[r];
                }
#pragma unroll
                for (int ks = 0; ks < 4; ++ks)
#pragma unroll
                    for (int i = 0; i < 4; ++i) {
                        const int j = 2*(i&1) + 4*((2*ks + (i>>1)) & 3) + 16*(ks>>1);
                        if (j < 16) own[ks*4+i] = packbf(s0[j], s0[j+1]);
                        else        own[ks*4+i] = packbf(s1[j-16], s1[j-15]);
                    }
            }
            ss += __shfl_xor(ss, 32, 64);
            ri = 1.0f / ss;
            f32x16 Ot;
#pragma unroll
            for (int i = 0; i < 16; ++i) Ot[i] = 0.f;
#pragma unroll
            for (int ks = 0; ks < 4; ++ks) {
                uint32_t sw0 = __shfl_xor(own[ks*4+0], 32, 64);
                uint32_t sw1 = __shfl_xor(own[ks*4+1], 32, 64);
                uint32_t sw2 = __shfl_xor(own[ks*4+2], 32, 64);
                uint32_t sw3 = __shfl_xor(own[ks*4+3], 32, 64);
                uint32_t w0 = hi ? sw2          : own[ks*4+0];
                uint32_t w1 = hi ? sw3          : own[ks*4+1];
                uint32_t w2 = hi ? own[ks*4+2]  : sw0;
                uint32_t w3 = hi ? own[ks*4+3]  : sw1;
                bf16x8 pf = frag_from_words(w0, w1, w2, w3);
                int dd = l31 & 15;
                bf16x8 vf = *(const bf16x8*)(sm + wv*2048 + dd*128
                                             + ((ks*32 + hi*16) ^ ((dd&7)<<4)));
                Ot = MFMA32(vf, pf, Ot);
            }
#pragma unroll
            for (int r = 0; r < 8; r += 2) {
                int d = (r&3) + 8*(r>>2) + 4*hi;
                *(uint32_t*)(sm + 32768 + q*256 + ((2*(wv*16 + d)) ^ ((q&7)<<4)))
                    = packbf(Ot[r]*ri, Ot[r+1]*ri);
            }
        }
    }
    __syncthreads();   // B5

    // P5: proj + residual -> write win2 token-major f32 (coalesced 64B segs)
    {
        f32x4 acc[4];
#pragma unroll
        for (int nt = 0; nt < 4; ++nt) acc[nt] = zero4();
#pragma unroll
        for (int ks = 0; ks < 4; ++ks) {
            int tok = fmt*16 + l15;
            bf16x8 afr = *(const bf16x8*)(sm + 32768 + tok*256 + ((ks*64 + l4*16) ^ ((tok&7)<<4)));
#pragma unroll
            for (int nt = 0; nt < 4; ++nt) {
                int n = fn0 + nt*16 + l15;
                bf16x8 bfr = *(const bf16x8*)(wprojT + n*128 + ks*32 + l4*8);
                acc[nt] = MFMA16(afr, bfr, acc[nt]);
            }
        }
        float* w2 = win2tm + (size_t)wid*8192;
#pragma unroll
        for (int nt = 0; nt < 4; ++nt) {
            int c = fn0 + nt*16 + l15;
            float bp = b_proj[c];
#pragma unroll
            for (int r = 0; r < 4; ++r) {
                int tok = fmt*16 + l4*4 + r;
                uint32_t w = winp[nt >> 1][r];
                float xr = uf((nt & 1) ? (w & 0xffff0000u) : (w << 16));
                w2[tok*128 + c] = xr + acc[nt][r] + bp;
            }
        }
    }
}

// ---------------------------------------------------------------------------
// kernel2: win2 -> LN2 (recomputed, in-place bf16) -> MLP -> +win2 -> out BCHW
// LDS 32768 = H[0:16K) win2bf16/h2 | G[16K:32K) g ; dump reuses H+G.
// ---------------------------------------------------------------------------
__global__ __launch_bounds__(512, 4) void swin_mlp(
    const float* __restrict__ win2tm,
    const float* __restrict__ ln2_g, const float* __restrict__ ln2_b,
    const float* __restrict__ b_fc1, const float* __restrict__ b_fc2,
    const bf16* __restrict__ wfc1T, const bf16* __restrict__ wfc2T,
    float* __restrict__ out)
{
    __shared__ __align__(16) char sm[32768];

    const int tid  = threadIdx.x;
    const int lane = tid & 63;
    const int wv   = tid >> 6;
    const int l15  = lane & 15;
    const int l4   = (lane >> 4) & 3;
    const int fmt  = wv >> 1;
    const int fn0  = (wv & 1) * 64;

    const int wid = ((blockIdx.x & 7) << 9) | (blockIdx.x >> 3);
    const int bb  = wid >> 10;
    const int hw  = (wid >> 5) & 31;
    const int wwi = wid & 31;
    const size_t obase = (size_t)bb * 8388608 + (size_t)hw * 2048 + (size_t)wwi * 8;
    float* outw = out + obase;
    const float* w2 = win2tm + (size_t)wid*8192;

    // stage win2 -> bf16 [tok][c] swizzled in H
#pragma unroll
    for (int it = 0; it < 4; ++it) {
        int idx = it*512 + tid;
        int tok = idx >> 5;
        int cg  = idx & 31;
        f32x4 v = *(const f32x4*)(w2 + tok*128 + cg*4);
        uint2 u;
        u.x = packbf(v[0], v[1]);
        u.y = packbf(v[2], v[3]);
        *(uint2*)(sm + tok*256 + ((cg*8) ^ ((tok&7)<<4))) = u;
    }
    __syncthreads();

    // LN2 in place (8 threads / token)
    {
        const int t = tid >> 3, p = tid & 7;
        const int swz = (t & 7) << 4;
        float vv[16];
        float s = 0.f, s2 = 0.f;
#pragma unroll
        for (int hlf = 0; hlf < 2; ++hlf) {
            bf16x8 xv = *(const bf16x8*)(sm + t*256 + ((p*32 + hlf*16) ^ swz));
#pragma unroll
            for (int e = 0; e < 8; ++e) { float f = (float)xv[e]; vv[hlf*8+e] = f; s += f; s2 += f*f; }
        }
#pragma unroll
        for (int m = 1; m < 8; m <<= 1) { s += __shfl_xor(s, m, 64); s2 += __shfl_xor(s2, m, 64); }
        const float mean = s * 0.0078125f;
        const float rs = rsqrtf(s2 * 0.0078125f - mean*mean + 1e-5f);
#pragma unroll
        for (int hlf = 0; hlf < 2; ++hlf) {
            bf16x8 hv;
#pragma unroll
            for (int e = 0; e < 8; ++e) {
                int c = p*16 + hlf*8 + e;
                hv[e] = (bf16)((vv[hlf*8+e] - mean) * rs * ln2_g[c] + ln2_b[c]);
            }
            *(bf16x8*)(sm + t*256 + ((p*32 + hlf*16) ^ swz)) = hv;
        }
    }
    __syncthreads();

    // MLP: 4 chunks, single g buffer
    f32x4 acc2[4];
#pragma unroll
    for (int nt = 0; nt < 4; ++nt) acc2[nt] = zero4();
#pragma unroll
    for (int c4 = 0; c4 < 4; ++c4) {
        {
            f32x4 a1[4];
#pragma unroll
            for (int nt = 0; nt < 4; ++nt) a1[nt] = zero4();
#pragma unroll
            for (int ks = 0; ks < 4; ++ks) {
                int tok = fmt*16 + l15;
                bf16x8 afr = *(const bf16x8*)(sm + tok*256 + ((ks*64 + l4*16) ^ ((tok&7)<<4)));
#pragma unroll
                for (int nt = 0; nt < 4; ++nt) {
                    int n = c4*128 + fn0 + nt*16 + l15;
                    bf16x8 bfr = *(const bf16x8*)(wfc1T + n*128 + ks*32 + l4*8);
                    a1[nt] = MFMA16(afr, bfr, a1[nt]);
                }
            }
#pragma unroll
            for (int nt = 0; nt < 4; ++nt) {
                int cl = fn0 + nt*16 + l15;
                float b1 = b_fc1[c4*128 + cl];
#pragma unroll
                for (int r = 0; r < 4; ++r) {
                    int tok = fmt*16 + l4*4 + r;
                    float u = a1[nt][r] + b1;
                    *(bf16*)(sm + 16384 + tok*256 + ((2*cl) ^ ((tok&7)<<4))) = (bf16)gelu_f(u);
                }
            }
        }
        __syncthreads();
#pragma unroll
        for (int ks = 0; ks < 4; ++ks) {
            int tok = fmt*16 + l15;
            bf16x8 afr = *(const bf16x8*)(sm + 16384 + tok*256 + ((ks*64 + l4*16) ^ ((tok&7)<<4)));
#pragma unroll
            for (int nt = 0; nt < 4; ++nt) {
                int n = fn0 + nt*16 + l15;
                bf16x8 bfr = *(const bf16x8*)(wfc2T + n*512 + c4*128 + ks*32 + l4*8);
                acc2[nt] = MFMA16(afr, bfr, acc2[nt]);
            }
        }
        __syncthreads();
    }

    // residual late (re-read win2 f32, L2-resident) + dump + BCHW write
    {
#pragma unroll
        for (int nt = 0; nt < 4; ++nt) {
            int c = fn0 + nt*16 + l15;
            float bf_ = b_fc2[c];
#pragma unroll
            for (int r = 0; r < 4; ++r) {
                int tok = fmt*16 + l4*4 + r;
                float res = w2[tok*128 + c];
                *(float*)(sm + tok*512 + ((c*4) ^ ((tok&15)<<4))) = res + acc2[nt][r] + bf_;
            }
        }
    }
    __syncthreads();
#pragma unroll
    for (int it = 0; it < 4; ++it) {
        int idx = it*512 + tid;
        int c = idx >> 4, t2 = idx & 15;
        int row = t2 >> 1, col0 = (t2 & 1) * 4;
        f32x4 v;
#pragma unroll
        for (int e = 0; e < 4; ++e) {
            int t = row*8 + col0 + e;
            v[e] = *(const float*)(sm + t*512 + ((c*4) ^ ((t&15)<<4)));
        }
        *(f32x4*)(outw + (size_t)c*65536 + row*256 + col0) = v;
    }
}

// ---------------------------------------------------------------------------
// fallback: R9 monolithic fused kernel (used if ws too small for win2tm)
// ---------------------------------------------------------------------------
__global__ __launch_bounds__(512, 4) void swin_fused(
    const float* __restrict__ x,
    const float* __restrict__ ln1_g, const float* __restrict__ ln1_b,
    const float* __restrict__ b_qkv, const float* __restrict__ b_proj,
    const float* __restrict__ ln2_g, const float* __restrict__ ln2_b,
    const float* __restrict__ b_fc1, const float* __restrict__ b_fc2,
    const bf16* __restrict__ wqkvT, const bf16* __restrict__ wprojT,
    const bf16* __restrict__ wfc1T, const bf16* __restrict__ wfc2T,
    const float* __restrict__ bN,
    float* __restrict__ out)
{
    __shared__ __align__(16) char sm[49152];

    const int tid  = threadIdx.x;
    const int lane = tid & 63;
    const int wv   = tid >> 6;
    const int l15  = lane & 15;
    const int l4   = (lane >> 4) & 3;
    const int l31  = lane & 31;
    const int hi   = lane >> 5;
    const int fmt  = wv >> 1;
    const int fn0  = (wv & 1) * 64;

    const int wid = ((blockIdx.x & 7) << 9) | (blockIdx.x >> 3);
    const int bb  = wid >> 10;
    const int hw  = (wid >> 5) & 31;
    const int wwi = wid & 31;
    const size_t base = (size_t)bb * 8388608 + (size_t)hw * 2048 + (size_t)wwi * 8;
    const float* xw   = x   + base;
    float*       outw = out + base;

#pragma unroll
    for (int it = 0; it < 4; ++it) {
        int idx = it*512 + tid;
        int c = idx >> 4, t2 = idx & 15;
        int row = t2 >> 1, col0 = (t2 & 1) * 4;
        f32x4 v = *(const f32x4*)(xw + (size_t)c*65536 + row*256 + col0);
#pragma unroll
        for (int e = 0; e < 4; ++e) {
            int t = row*8 + col0 + e;
            *(bf16*)(sm + t*256 + ((2*c) ^ ((t&7)<<4))) = (bf16)v[e];
        }
    }
    __syncthreads();

    uint32_t winp[2][4];
#pragma unroll
    for (int r = 0; r < 4; ++r) {
        int tok = fmt*16 + l4*4 + r;
        int swz = (tok & 7) << 4;
        const char* rowp = sm + tok*256;
        uint32_t c0 = *(const uint16_t*)(rowp + ((2*(fn0 +  0 + l15)) ^ swz));
        uint32_t c1 = *(const uint16_t*)(rowp + ((2*(fn0 + 16 + l15)) ^ swz));
        uint32_t c2 = *(const uint16_t*)(rowp + ((2*(fn0 + 32 + l15)) ^ swz));
        uint32_t c3 = *(const uint16_t*)(rowp + ((2*(fn0 + 48 + l15)) ^ swz));
        winp[0][r] = c0 | (c1 << 16);
        winp[1][r] = c2 | (c3 << 16);
    }

    {
        const int t = tid >> 3, p = tid & 7;
        const int swz = (t & 7) << 4;
        float vv[16];
        float s = 0.f, s2 = 0.f;
#pragma unroll
        for (int hlf = 0; hlf < 2; ++hlf) {
            bf16x8 xv = *(const bf16x8*)(sm + t*256 + ((p*32 + hlf*16) ^ swz));
#pragma unroll
            for (int e = 0; e < 8; ++e) { float f = (float)xv[e]; vv[hlf*8+e] = f; s += f; s2 += f*f; }
        }
#pragma unroll
        for (int m = 1; m < 8; m <<= 1) { s += __shfl_xor(s, m, 64); s2 += __shfl_xor(s2, m, 64); }
        const float mean = s * 0.0078125f;
        const float rs = rsqrtf(s2 * 0.0078125f - mean*mean + 1e-5f);
#pragma unroll
        for (int hlf = 0; hlf < 2; ++hlf) {
            bf16x8 hv;
#pragma unroll
            for (int e = 0; e < 8; ++e) {
                int c = p*16 + hlf*8 + e;
                hv[e] = (bf16)((vv[hlf*8+e] - mean) * rs * ln1_g[c] + ln1_b[c]);
            }
            *(bf16x8*)(sm + 16384 + t*256 + ((p*32 + hlf*16) ^ swz)) = hv;
        }
    }
    __syncthreads();

    {
        const float SCALE = 0.35355339059327373f;
        const int nq0 = wv * 32;
        const int nv  = 256 + wv*16 + l15;
        const float bb0 = b_qkv[nq0 + l15];
        const float bb1 = b_qkv[nq0 + 16 + l15];
        const float bbv = b_qkv[nv];
        const bool isq = (nq0 < 128);
        char* rb = isq ? (sm + 16384) : (sm + 32768);
        const float sc = isq ? SCALE : 1.0f;
        const int c0 = (nq0 & 127) + l15;
        const int c1 = ((nq0 + 16) & 127) + l15;
#pragma unroll
        for (int half = 0; half < 2; ++half) {
            f32x4 a0[2], a1[2], avh[2];
#pragma unroll
            for (int m2 = 0; m2 < 2; ++m2) { a0[m2] = zero4(); a1[m2] = zero4(); avh[m2] = zero4(); }
#pragma unroll
            for (int ks = 0; ks < 4; ++ks) {
                bf16x8 bq0 = *(const bf16x8*)(wqkvT + (nq0      + l15)*128 + ks*32 + l4*8);
                bf16x8 bq1 = *(const bf16x8*)(wqkvT + (nq0 + 16 + l15)*128 + ks*32 + l4*8);
                bf16x8 bv  = *(const bf16x8*)(wqkvT + nv*128 + ks*32 + l4*8);
#pragma unroll
                for (int m2 = 0; m2 < 2; ++m2) {
                    int tok = half*32 + m2*16 + l15;
                    bf16x8 afr = *(const bf16x8*)(sm + 16384 + tok*256 + ((ks*64 + l4*16) ^ ((tok&7)<<4)));
                    a0[m2]  = MFMA16(afr, bq0, a0[m2]);
                    a1[m2]  = MFMA16(afr, bq1, a1[m2]);
                    avh[m2] = MFMA16(afr, bv,  avh[m2]);
                }
            }
            __syncthreads();
#pragma unroll
            for (int m2 = 0; m2 < 2; ++m2)
#pragma unroll
                for (int r = 0; r < 4; ++r) {
                    int tok = half*32 + m2*16 + l4*4 + r;
                    int swz = (tok & 7) << 4;
                    *(bf16*)(rb + tok*256 + ((2*c0) ^ swz)) = (bf16)((a0[m2][r] + bb0) * sc);
                    *(bf16*)(rb + tok*256 + ((2*c1) ^ swz)) = (bf16)((a1[m2][r] + bb1) * sc);
                }
            {
                int d = l15;
                char* vb = sm + wv*2048 + d*128;
                int sz = (d & 7) << 4;
#pragma unroll
                for (int m2 = 0; m2 < 2; ++m2) {
                    int t0 = half*32 + m2*16 + l4*4;
                    *(uint32_t*)(vb + ((2*t0)     ^ sz)) = packbf(avh[m2][0]+bbv, avh[m2][1]+bbv);
                    *(uint32_t*)(vb + ((2*t0 + 4) ^ sz)) = packbf(avh[m2][2]+bbv, avh[m2][3]+bbv);
                }
            }
        }
    }
    __syncthreads();

    {
        bf16x8 kf[2];
#pragma unroll
        for (int tk = 0; tk < 2; ++tk) {
            int tok = tk*32 + l31;
            kf[tk] = *(const bf16x8*)(sm + 32768 + tok*256 + ((wv*32 + hi*16) ^ ((tok&7)<<4)));
        }
        __syncthreads();
#pragma unroll
        for (int tq = 0; tq < 2; ++tq) {
            int q = tq*32 + l31;
            bf16x8 qf = *(const bf16x8*)(sm + 16384 + q*256 + ((wv*32 + hi*16) ^ ((q&7)<<4)));
            const float* bq = bN + wv*4096 + q*64 + 4*hi;
            float ss, ri;
            uint32_t own[16];
            {
                f32x16 s0, s1;
#pragma unroll
                for (int g4 = 0; g4 < 4; ++g4) {
                    f32x4 b0 = *(const f32x4*)(bq + g4*8);
                    f32x4 b1 = *(const f32x4*)(bq + 32 + g4*8);
#pragma unroll
                    for (int e = 0; e < 4; ++e) { s0[g4*4+e] = b0[e]; s1[g4*4+e] = b1[e]; }
                }
                s0 = MFMA32(kf[0], qf, s0);
                s1 = MFMA32(kf[1], qf, s1);
                ss = 0.f;
#pragma unroll
                for (int r = 0; r < 16; ++r) {
                    s0[r] = __expf(s0[r]);
                    s1[r] = __expf(s1[r]);
                    ss += s0[r] + s1[r];
                }
#pragma unroll
                for (int ks = 0; ks < 4; ++ks)
#pragma unroll
                    for (int i = 0; i < 4; ++i) {
                        const int j = 2*(i&1) + 4*((2*ks + (i>>1)) & 3) + 16*(ks>>1);
                        if (j < 16) own[ks*4+i] = packbf(s0[j], s0[j+1]);
                        else        own[ks*4+i] = packbf(s1[j-16], s1[j-15]);
                    }
            }
            ss += __shfl_xor(ss, 32, 64);
            ri = 1.0f / ss;
            f32x16 Ot;
#pragma unroll
            for (int i = 0; i < 16; ++i) Ot[i] = 0.f;
#pragma unroll
            for (int ks = 0; ks < 4; ++ks) {
                uint32_t sw0 = __shfl_xor(own[ks*4+0], 32, 64);
                uint32_t sw1 = __shfl_xor(own[ks*4+1], 32, 64);
                uint32_t sw2 = __shfl_xor(own[ks*4+2], 32, 64);
                uint32_t sw3 = __shfl_xor(own[ks*4+3], 32, 64);
                uint32_t w0 = hi ? sw2          : own[ks*4+0];
                uint32_t w1 = hi ? sw3          : own[ks*4+1];
                uint32_t w2 = hi ? own[ks*4+2]  : sw0;
                uint32_t w3 = hi ? own[ks*4+3]  : sw1;
                bf16x8 pf = frag_from_words(w0, w1, w2, w3);
                int dd = l31 & 15;
                bf16x8 vf = *(const bf16x8*)(sm + wv*2048 + dd*128
                                             + ((ks*32 + hi*16) ^ ((dd&7)<<4)));
                Ot = MFMA32(vf, pf, Ot);
            }
#pragma unroll
            for (int r = 0; r < 8; r += 2) {
                int d = (r&3) + 8*(r>>2) + 4*hi;
                *(uint32_t*)(sm + 32768 + q*256 + ((2*(wv*16 + d)) ^ ((q&7)<<4)))
                    = packbf(Ot[r]*ri, Ot[r+1]*ri);
            }
        }
    }
    __syncthreads();

    float win2[4][4];
    {
        f32x4 acc[4];
#pragma unroll
        for (int nt = 0; nt < 4; ++nt) acc[nt] = zero4();
#pragma unroll
        for (int ks = 0; ks < 4; ++ks) {
            int tok = fmt*16 + l15;
            bf16x8 afr = *(const bf16x8*)(sm + 32768 + tok*256 + ((ks*64 + l4*16) ^ ((tok&7)<<4)));
#pragma unroll
            for (int nt = 0; nt < 4; ++nt) {
                int n = fn0 + nt*16 + l15;
                bf16x8 bfr = *(const bf16x8*)(wprojT + n*128 + ks*32 + l4*8);
                acc[nt] = MFMA16(afr, bfr, acc[nt]);
            }
        }
#pragma unroll
        for (int nt = 0; nt < 4; ++nt) {
            float bp = b_proj[fn0 + nt*16 + l15];
#pragma unroll
            for (int r = 0; r < 4; ++r) {
                uint32_t w = winp[nt >> 1][r];
                float xr = uf((nt & 1) ? (w & 0xffff0000u) : (w << 16));
                win2[nt][r] = xr + acc[nt][r] + bp;
            }
        }
    }

    {
        float s[4], s2[4];
#pragma unroll
        for (int r = 0; r < 4; ++r) {
            s[r]  = win2[0][r] + win2[1][r] + win2[2][r] + win2[3][r];
            s2[r] = win2[0][r]*win2[0][r] + win2[1][r]*win2[1][r]
                  + win2[2][r]*win2[2][r] + win2[3][r]*win2[3][r];
#pragma unroll
            for (int m = 1; m < 16; m <<= 1) {
                s[r]  += __shfl_xor(s[r],  m, 64);
                s2[r] += __shfl_xor(s2[r], m, 64);
            }
        }
        float2* scr = (float2*)sm;
        if (l15 == 0) {
#pragma unroll
            for (int r = 0; r < 4; ++r) {
                int tok = fmt*16 + l4*4 + r;
                scr[tok*2 + (wv&1)] = make_float2(s[r], s2[r]);
            }
        }
        __syncthreads();
        float mean[4], rstd[4];
#pragma unroll
        for (int r = 0; r < 4; ++r) {
            int tok = fmt*16 + l4*4 + r;
            float2 p = scr[tok*2 + ((wv&1)^1)];
            float tot = s[r] + p.x, tot2 = s2[r] + p.y;
            float m = tot * 0.0078125f;
            mean[r] = m;
            rstd[r] = rsqrtf(tot2*0.0078125f - m*m + 1e-5f);
        }
#pragma unroll
        for (int nt = 0; nt < 4; ++nt) {
            int c = fn0 + nt*16 + l15;
            float gg = ln2_g[c], bb2 = ln2_b[c];
#pragma unroll
            for (int r = 0; r < 4; ++r) {
                int tok = fmt*16 + l4*4 + r;
                *(bf16*)(sm + 16384 + tok*256 + ((2*c) ^ ((tok&7)<<4)))
                    = (bf16)((win2[nt][r] - mean[r]) * rstd[r] * gg + bb2);
            }
        }
    }
    __syncthreads();

    {
        f32x4 acc2[4];
#pragma unroll
        for (int nt = 0; nt < 4; ++nt) acc2[nt] = zero4();
#pragma unroll
        for (int c4 = 0; c4 < 4; ++c4) {
            char* gbuf = (c4 & 1) ? (sm + 32768) : sm;
            {
                f32x4 a1[4];
#pragma unroll
                for (int nt = 0; nt < 4; ++nt) a1[nt] = zero4();
#pragma unroll
                for (int ks = 0; ks < 4; ++ks) {
                    int tok = fmt*16 + l15;
                    bf16x8 afr = *(const bf16x8*)(sm + 16384 + tok*256 + ((ks*64 + l4*16) ^ ((tok&7)<<4)));
#pragma unroll
                    for (int nt = 0; nt < 4; ++nt) {
                        int n = c4*128 + fn0 + nt*16 + l15;
                        bf16x8 bfr = *(const bf16x8*)(wfc1T + n*128 + ks*32 + l4*8);
                        a1[nt] = MFMA16(afr, bfr, a1[nt]);
                    }
                }
#pragma unroll
                for (int nt = 0; nt < 4; ++nt) {
                    int cl = fn0 + nt*16 + l15;
                    float b1 = b_fc1[c4*128 + cl];
#pragma unroll
                    for (int r = 0; r < 4; ++r) {
                        int tok = fmt*16 + l4*4 + r;
                        float u = a1[nt][r] + b1;
                        *(bf16*)(gbuf + tok*256 + ((2*cl) ^ ((tok&7)<<4))) = (bf16)gelu_f(u);
                    }
                }
            }
            __syncthreads();
#pragma unroll
            for (int ks = 0; ks < 4; ++ks) {
                int tok = fmt*16 + l15;
                bf16x8 afr = *(const bf16x8*)(gbuf + tok*256 + ((ks*64 + l4*16) ^ ((tok&7)<<4)));
#pragma unroll
                for (int nt = 0; nt < 4; ++nt) {
                    int n = fn0 + nt*16 + l15;
                    bf16x8 bfr = *(const bf16x8*)(wfc2T + n*512 + c4*128 + ks*32 + l4*8);
                    acc2[nt] = MFMA16(afr, bfr, acc2[nt]);
                }
            }
        }
#pragma unroll
        for (int nt = 0; nt < 4; ++nt) {
            float bf_ = b_fc2[fn0 + nt*16 + l15];
#pragma unroll
            for (int r = 0; r < 4; ++r) win2[nt][r] += acc2[nt][r] + bf_;
        }
    }
    __syncthreads();

#pragma unroll
    for (int nt = 0; nt < 4; ++nt)
#pragma unroll
        for (int r = 0; r < 4; ++r) {
            int tok = fmt*16 + l4*4 + r;
            int c   = fn0 + nt*16 + l15;
            *(float*)(sm + tok*512 + ((c*4) ^ ((tok&15)<<4))) = win2[nt][r];
        }
    __syncthreads();
#pragma unroll
    for (int it = 0; it < 4; ++it) {
        int idx = it*512 + tid;
        int c = idx >> 4, t2 = idx & 15;
        int row = t2 >> 1, col0 = (t2 & 1) * 4;
        f32x4 v;
#pragma unroll
        for (int e = 0; e < 4; ++e) {
            int t = row*8 + col0 + e;
            v[e] = *(const float*)(sm + t*512 + ((c*4) ^ ((t&15)<<4)));
        }
        *(f32x4*)(outw + (size_t)c*65536 + row*256 + col0) = v;
    }
}

extern "C" void kernel_launch(void* const* d_in, const int* in_sizes, int n_in,
                              void* d_out, int out_size, void* d_ws, size_t ws_size,
                              hipStream_t stream) {
    const float* x      = (const float*)d_in[0];
    const float* ln1_g  = (const float*)d_in[1];
    const float* ln1_b  = (const float*)d_in[2];
    const float* w_qkv  = (const float*)d_in[3];
    const float* b_qkv  = (const float*)d_in[4];
    const float* w_proj = (const float*)d_in[5];
    const float* b_proj = (const float*)d_in[6];
    const float* btab   = (const float*)d_in[7];
    const float* ln2_g  = (const float*)d_in[8];
    const float* ln2_b  = (const float*)d_in[9];
    const float* w_fc1  = (const float*)d_in[10];
    const float* b_fc1  = (const float*)d_in[11];
    const float* w_fc2  = (const float*)d_in[12];
    const float* b_fc2  = (const float*)d_in[13];
    const int*   relix  = (const int*)d_in[14];
    float* out = (float*)d_out;

    char* ws = (char*)d_ws;
    bf16*  wqkvT  = (bf16*)(ws);
    bf16*  wprojT = (bf16*)(ws + 98304);
    bf16*  wfc1T  = (bf16*)(ws + 131072);
    bf16*  wfc2T  = (bf16*)(ws + 262144);
    float* bN     = (float*)(ws + 393216);
    float* win2tm = (float*)(ws + 524288);

    prep_kernel<<<dim3(448), dim3(512), 0, stream>>>(
        w_qkv, w_proj, w_fc1, w_fc2, btab, relix,
        wqkvT, wprojT, wfc1T, wfc2T, bN);

    const size_t need = 524288ull + 134217728ull;
    if (ws_size >= need) {
        swin_attn<<<dim3(4096), dim3(512), 0, stream>>>(
            x, ln1_g, ln1_b, b_qkv, b_proj, wqkvT, wprojT, bN, win2tm);
        swin_mlp<<<dim3(4096), dim3(512), 0, stream>>>(
            win2tm, ln2_g, ln2_b, b_fc1, b_fc2, wfc1T, wfc2T, out);
    } else {
        swin_fused<<<dim3(4096), dim3(512), 0, stream>>>(
            x, ln1_g, ln1_b, b_qkv, b_proj, ln2_g, ln2_b, b_fc1, b_fc2,
            wqkvT, wprojT, wfc1T, wfc2T, bN, out);
    }
}

// Round 11
// 761.004 us; speedup vs baseline: 1.0367x; 1.0367x over previous
//
#include <hip/hip_runtime.h>
#include <hip/hip_bf16.h>
#include <stdint.h>

typedef __bf16 bf16;
typedef __bf16 bf16x8 __attribute__((ext_vector_type(8)));
typedef float  f32x4  __attribute__((ext_vector_type(4)));
typedef float  f32x16 __attribute__((ext_vector_type(16)));

#define MFMA16(a,b,c) __builtin_amdgcn_mfma_f32_16x16x32_bf16(a,b,c,0,0,0)
#define MFMA32(a,b,c) __builtin_amdgcn_mfma_f32_32x32x16_bf16(a,b,c,0,0,0)

__device__ __forceinline__ f32x4 zero4() { f32x4 z; z[0]=0.f; z[1]=0.f; z[2]=0.f; z[3]=0.f; return z; }

__device__ __forceinline__ uint32_t packbf(float lo, float hi) {
    union { bf16 b[2]; uint32_t u; } t;
    t.b[0] = (bf16)lo; t.b[1] = (bf16)hi;
    return t.u;
}
__device__ __forceinline__ bf16x8 frag_from_words(uint32_t w0, uint32_t w1, uint32_t w2, uint32_t w3) {
    union { uint32_t u[4]; bf16x8 v; } t;
    t.u[0] = w0; t.u[1] = w1; t.u[2] = w2; t.u[3] = w3;
    return t.v;
}
__device__ __forceinline__ float uf(uint32_t u) {
    union { uint32_t u; float f; } t; t.u = u; return t.f;
}
// fast GELU (tanh form, max err ~3e-3)
__device__ __forceinline__ float gelu_f(float u) {
    float u2 = u * u;
    float y  = u * (0.7978845608f + 0.0356774081f * u2);
    float e  = __expf(2.0f * y);
    float t  = 1.0f - 2.0f / (e + 1.0f);
    return 0.5f * u * (1.0f + t);
}

// ---------------------------------------------------------------------------
// prep: weights f32 -> bf16 [n][k]; bias matrix natural: bN[h][q][k]
// ws layout (bytes):
//   0      : wqkvT  [384][128] bf16   (98304)
//   98304  : wprojT [128][128] bf16   (32768)
//   131072 : wfc1T  [512][128] bf16   (131072)
//   262144 : wfc2T  [128][512] bf16   (131072)
//   393216 : bN     [8][64][64] f32   (131072)
//   524288 : win2tm [4096][64][128] f32 (134217728)   [split path only]
// ---------------------------------------------------------------------------
__global__ __launch_bounds__(512) void prep_kernel(
    const float* __restrict__ wqkv, const float* __restrict__ wproj,
    const float* __restrict__ wfc1, const float* __restrict__ wfc2,
    const float* __restrict__ btab, const int* __restrict__ relidx,
    bf16* __restrict__ wqkvT, bf16* __restrict__ wprojT,
    bf16* __restrict__ wfc1T, bf16* __restrict__ wfc2T,
    float* __restrict__ bN)
{
    int i = blockIdx.x * 512 + threadIdx.x;
    if (i < 49152) { int n = i >> 7, k = i & 127; wqkvT[i] = (bf16)wqkv[k*384 + n]; return; }
    i -= 49152;
    if (i < 16384) { int n = i >> 7, k = i & 127; wprojT[i] = (bf16)wproj[k*128 + n]; return; }
    i -= 16384;
    if (i < 65536) { int n = i >> 7, k = i & 127; wfc1T[i] = (bf16)wfc1[k*512 + n]; return; }
    i -= 65536;
    if (i < 65536) { int n = i >> 9, k = i & 511; wfc2T[i] = (bf16)wfc2[k*128 + n]; return; }
    i -= 65536;
    if (i < 32768) { int h = i >> 12, q = (i >> 6) & 63, k = i & 63;
                     bN[i] = btab[relidx[q*64 + k]*8 + h]; }
}

// ---------------------------------------------------------------------------
// kernel1: x -> LN1 -> QKV -> attention -> proj + residual -> win2 (token-major f32)
// (identical to R10)
// ---------------------------------------------------------------------------
__global__ __launch_bounds__(512, 4) void swin_attn(
    const float* __restrict__ x,
    const float* __restrict__ ln1_g, const float* __restrict__ ln1_b,
    const float* __restrict__ b_qkv, const float* __restrict__ b_proj,
    const bf16* __restrict__ wqkvT, const bf16* __restrict__ wprojT,
    const float* __restrict__ bN,
    float* __restrict__ win2tm)
{
    __shared__ __align__(16) char sm[49152];

    const int tid  = threadIdx.x;
    const int lane = tid & 63;
    const int wv   = tid >> 6;
    const int l15  = lane & 15;
    const int l4   = (lane >> 4) & 3;
    const int l31  = lane & 31;
    const int hi   = lane >> 5;
    const int fmt  = wv >> 1;
    const int fn0  = (wv & 1) * 64;

    const int wid = ((blockIdx.x & 7) << 9) | (blockIdx.x >> 3);
    const int bb  = wid >> 10;
    const int hw  = (wid >> 5) & 31;
    const int wwi = wid & 31;
    const size_t base = (size_t)bb * 8388608 + (size_t)hw * 2048 + (size_t)wwi * 8;
    const float* xw = x + base;

#pragma unroll
    for (int it = 0; it < 4; ++it) {
        int idx = it*512 + tid;
        int c = idx >> 4, t2 = idx & 15;
        int row = t2 >> 1, col0 = (t2 & 1) * 4;
        f32x4 v = *(const f32x4*)(xw + (size_t)c*65536 + row*256 + col0);
#pragma unroll
        for (int e = 0; e < 4; ++e) {
            int t = row*8 + col0 + e;
            *(bf16*)(sm + t*256 + ((2*c) ^ ((t&7)<<4))) = (bf16)v[e];
        }
    }
    __syncthreads();   // B1

    uint32_t winp[2][4];
#pragma unroll
    for (int r = 0; r < 4; ++r) {
        int tok = fmt*16 + l4*4 + r;
        int swz = (tok & 7) << 4;
        const char* rowp = sm + tok*256;
        uint32_t c0 = *(const uint16_t*)(rowp + ((2*(fn0 +  0 + l15)) ^ swz));
        uint32_t c1 = *(const uint16_t*)(rowp + ((2*(fn0 + 16 + l15)) ^ swz));
        uint32_t c2 = *(const uint16_t*)(rowp + ((2*(fn0 + 32 + l15)) ^ swz));
        uint32_t c3 = *(const uint16_t*)(rowp + ((2*(fn0 + 48 + l15)) ^ swz));
        winp[0][r] = c0 | (c1 << 16);
        winp[1][r] = c2 | (c3 << 16);
    }

    {
        const int t = tid >> 3, p = tid & 7;
        const int swz = (t & 7) << 4;
        float vv[16];
        float s = 0.f, s2 = 0.f;
#pragma unroll
        for (int hlf = 0; hlf < 2; ++hlf) {
            bf16x8 xv = *(const bf16x8*)(sm + t*256 + ((p*32 + hlf*16) ^ swz));
#pragma unroll
            for (int e = 0; e < 8; ++e) { float f = (float)xv[e]; vv[hlf*8+e] = f; s += f; s2 += f*f; }
        }
#pragma unroll
        for (int m = 1; m < 8; m <<= 1) { s += __shfl_xor(s, m, 64); s2 += __shfl_xor(s2, m, 64); }
        const float mean = s * 0.0078125f;
        const float rs = rsqrtf(s2 * 0.0078125f - mean*mean + 1e-5f);
#pragma unroll
        for (int hlf = 0; hlf < 2; ++hlf) {
            bf16x8 hv;
#pragma unroll
            for (int e = 0; e < 8; ++e) {
                int c = p*16 + hlf*8 + e;
                hv[e] = (bf16)((vv[hlf*8+e] - mean) * rs * ln1_g[c] + ln1_b[c]);
            }
            *(bf16x8*)(sm + 16384 + t*256 + ((p*32 + hlf*16) ^ swz)) = hv;
        }
    }
    __syncthreads();   // B2

    {
        const float SCALE = 0.35355339059327373f;
        const int nq0 = wv * 32;
        const int nv  = 256 + wv*16 + l15;
        const float bb0 = b_qkv[nq0 + l15];
        const float bb1 = b_qkv[nq0 + 16 + l15];
        const float bbv = b_qkv[nv];
        const bool isq = (nq0 < 128);
        char* rb = isq ? (sm + 16384) : (sm + 32768);
        const float sc = isq ? SCALE : 1.0f;
        const int c0 = (nq0 & 127) + l15;
        const int c1 = ((nq0 + 16) & 127) + l15;
#pragma unroll
        for (int half = 0; half < 2; ++half) {
            f32x4 a0[2], a1[2], avh[2];
#pragma unroll
            for (int m2 = 0; m2 < 2; ++m2) { a0[m2] = zero4(); a1[m2] = zero4(); avh[m2] = zero4(); }
#pragma unroll
            for (int ks = 0; ks < 4; ++ks) {
                bf16x8 bq0 = *(const bf16x8*)(wqkvT + (nq0      + l15)*128 + ks*32 + l4*8);
                bf16x8 bq1 = *(const bf16x8*)(wqkvT + (nq0 + 16 + l15)*128 + ks*32 + l4*8);
                bf16x8 bv  = *(const bf16x8*)(wqkvT + nv*128 + ks*32 + l4*8);
#pragma unroll
                for (int m2 = 0; m2 < 2; ++m2) {
                    int tok = half*32 + m2*16 + l15;
                    bf16x8 afr = *(const bf16x8*)(sm + 16384 + tok*256 + ((ks*64 + l4*16) ^ ((tok&7)<<4)));
                    a0[m2]  = MFMA16(afr, bq0, a0[m2]);
                    a1[m2]  = MFMA16(afr, bq1, a1[m2]);
                    avh[m2] = MFMA16(afr, bv,  avh[m2]);
                }
            }
            __syncthreads();   // B3a / B3b
#pragma unroll
            for (int m2 = 0; m2 < 2; ++m2)
#pragma unroll
                for (int r = 0; r < 4; ++r) {
                    int tok = half*32 + m2*16 + l4*4 + r;
                    int swz = (tok & 7) << 4;
                    *(bf16*)(rb + tok*256 + ((2*c0) ^ swz)) = (bf16)((a0[m2][r] + bb0) * sc);
                    *(bf16*)(rb + tok*256 + ((2*c1) ^ swz)) = (bf16)((a1[m2][r] + bb1) * sc);
                }
            {
                int d = l15;
                char* vb = sm + wv*2048 + d*128;
                int sz = (d & 7) << 4;
#pragma unroll
                for (int m2 = 0; m2 < 2; ++m2) {
                    int t0 = half*32 + m2*16 + l4*4;
                    *(uint32_t*)(vb + ((2*t0)     ^ sz)) = packbf(avh[m2][0]+bbv, avh[m2][1]+bbv);
                    *(uint32_t*)(vb + ((2*t0 + 4) ^ sz)) = packbf(avh[m2][2]+bbv, avh[m2][3]+bbv);
                }
            }
        }
    }
    __syncthreads();   // B3

    {
        bf16x8 kf[2];
#pragma unroll
        for (int tk = 0; tk < 2; ++tk) {
            int tok = tk*32 + l31;
            kf[tk] = *(const bf16x8*)(sm + 32768 + tok*256 + ((wv*32 + hi*16) ^ ((tok&7)<<4)));
        }
        __syncthreads();   // B4
#pragma unroll
        for (int tq = 0; tq < 2; ++tq) {
            int q = tq*32 + l31;
            bf16x8 qf = *(const bf16x8*)(sm + 16384 + q*256 + ((wv*32 + hi*16) ^ ((q&7)<<4)));
            const float* bq = bN + wv*4096 + q*64 + 4*hi;
            float ss, ri;
            uint32_t own[16];
            {
                f32x16 s0, s1;
#pragma unroll
                for (int g4 = 0; g4 < 4; ++g4) {
                    f32x4 b0 = *(const f32x4*)(bq + g4*8);
                    f32x4 b1 = *(const f32x4*)(bq + 32 + g4*8);
#pragma unroll
                    for (int e = 0; e < 4; ++e) { s0[g4*4+e] = b0[e]; s1[g4*4+e] = b1[e]; }
                }
                s0 = MFMA32(kf[0], qf, s0);
                s1 = MFMA32(kf[1], qf, s1);
                ss = 0.f;
#pragma unroll
                for (int r = 0; r < 16; ++r) {
                    s0[r] = __expf(s0[r]);
                    s1[r] = __expf(s1[r]);
                    ss += s0[r] + s1[r];
                }
#pragma unroll
                for (int ks = 0; ks < 4; ++ks)
#pragma unroll
                    for (int i = 0; i < 4; ++i) {
                        const int j = 2*(i&1) + 4*((2*ks + (i>>1)) & 3) + 16*(ks>>1);
                        if (j < 16) own[ks*4+i] = packbf(s0[j], s0[j+1]);
                        else        own[ks*4+i] = packbf(s1[j-16], s1[j-15]);
                    }
            }
            ss += __shfl_xor(ss, 32, 64);
            ri = 1.0f / ss;
            f32x16 Ot;
#pragma unroll
            for (int i = 0; i < 16; ++i) Ot[i] = 0.f;
#pragma unroll
            for (int ks = 0; ks < 4; ++ks) {
                uint32_t sw0 = __shfl_xor(own[ks*4+0], 32, 64);
                uint32_t sw1 = __shfl_xor(own[ks*4+1], 32, 64);
                uint32_t sw2 = __shfl_xor(own[ks*4+2], 32, 64);
                uint32_t sw3 = __shfl_xor(own[ks*4+3], 32, 64);
                uint32_t w0 = hi ? sw2          : own[ks*4+0];
                uint32_t w1 = hi ? sw3          : own[ks*4+1];
                uint32_t w2 = hi ? own[ks*4+2]  : sw0;
                uint32_t w3 = hi ? own[ks*4+3]  : sw1;
                bf16x8 pf = frag_from_words(w0, w1, w2, w3);
                int dd = l31 & 15;
                bf16x8 vf = *(const bf16x8*)(sm + wv*2048 + dd*128
                                             + ((ks*32 + hi*16) ^ ((dd&7)<<4)));
                Ot = MFMA32(vf, pf, Ot);
            }
#pragma unroll
            for (int r = 0; r < 8; r += 2) {
                int d = (r&3) + 8*(r>>2) + 4*hi;
                *(uint32_t*)(sm + 32768 + q*256 + ((2*(wv*16 + d)) ^ ((q&7)<<4)))
                    = packbf(Ot[r]*ri, Ot[r+1]*ri);
            }
        }
    }
    __syncthreads();   // B5

    {
        f32x4 acc[4];
#pragma unroll
        for (int nt = 0; nt < 4; ++nt) acc[nt] = zero4();
#pragma unroll
        for (int ks = 0; ks < 4; ++ks) {
            int tok = fmt*16 + l15;
            bf16x8 afr = *(const bf16x8*)(sm + 32768 + tok*256 + ((ks*64 + l4*16) ^ ((tok&7)<<4)));
#pragma unroll
            for (int nt = 0; nt < 4; ++nt) {
                int n = fn0 + nt*16 + l15;
                bf16x8 bfr = *(const bf16x8*)(wprojT + n*128 + ks*32 + l4*8);
                acc[nt] = MFMA16(afr, bfr, acc[nt]);
            }
        }
        float* w2 = win2tm + (size_t)wid*8192;
#pragma unroll
        for (int nt = 0; nt < 4; ++nt) {
            int c = fn0 + nt*16 + l15;
            float bp = b_proj[c];
#pragma unroll
            for (int r = 0; r < 4; ++r) {
                int tok = fmt*16 + l4*4 + r;
                uint32_t w = winp[nt >> 1][r];
                float xr = uf((nt & 1) ? (w & 0xffff0000u) : (w << 16));
                w2[tok*128 + c] = xr + acc[nt][r] + bp;
            }
        }
    }
}

// fc1 chunk: h2 (H at sm[0:16K)) @ wfc1T cols [c4*128 ...] -> gelu -> gb
// two 2-column passes to keep a1 at 8 AGPR.
__device__ __forceinline__ void mlp_fc1_chunk(
    const char* __restrict__ sm, char* __restrict__ gb,
    const bf16* __restrict__ wfc1T, const float* __restrict__ b_fc1,
    int c4, int fmt, int fn0, int l15, int l4)
{
#pragma unroll
    for (int p2 = 0; p2 < 2; ++p2) {
        f32x4 a1[2];
        a1[0] = zero4(); a1[1] = zero4();
#pragma unroll
        for (int ks = 0; ks < 4; ++ks) {
            int tok = fmt*16 + l15;
            bf16x8 afr = *(const bf16x8*)(sm + tok*256 + ((ks*64 + l4*16) ^ ((tok&7)<<4)));
#pragma unroll
            for (int n2 = 0; n2 < 2; ++n2) {
                int n = c4*128 + fn0 + (p2*2 + n2)*16 + l15;
                bf16x8 bfr = *(const bf16x8*)(wfc1T + n*128 + ks*32 + l4*8);
                a1[n2] = MFMA16(afr, bfr, a1[n2]);
            }
        }
#pragma unroll
        for (int n2 = 0; n2 < 2; ++n2) {
            int cl = fn0 + (p2*2 + n2)*16 + l15;
            float b1 = b_fc1[c4*128 + cl];
#pragma unroll
            for (int r = 0; r < 4; ++r) {
                int tok = fmt*16 + l4*4 + r;
                float u = a1[n2][r] + b1;
                *(bf16*)(gb + tok*256 + ((2*cl) ^ ((tok&7)<<4))) = (bf16)gelu_f(u);
            }
        }
    }
}

// ---------------------------------------------------------------------------
// kernel2: win2 -> LN2 -> MLP (ping-pong g, fc1(i+1) overlapped with fc2(i))
// LDS 49152 = H[0:16K) h2 | gA[16K:32K) | gB[32K:48K); dump reuses [0:32K).
// Register budget: acc2 16 + a1 8 = 24 AGPR + ~56 arch = ~80 -> 3 blocks/CU.
// ---------------------------------------------------------------------------
__global__ __launch_bounds__(512, 4) void swin_mlp(
    const float* __restrict__ win2tm,
    const float* __restrict__ ln2_g, const float* __restrict__ ln2_b,
    const float* __restrict__ b_fc1, const float* __restrict__ b_fc2,
    const bf16* __restrict__ wfc1T, const bf16* __restrict__ wfc2T,
    float* __restrict__ out)
{
    __shared__ __align__(16) char sm[49152];

    const int tid  = threadIdx.x;
    const int lane = tid & 63;
    const int wv   = tid >> 6;
    const int l15  = lane & 15;
    const int l4   = (lane >> 4) & 3;
    const int fmt  = wv >> 1;
    const int fn0  = (wv & 1) * 64;

    const int wid = ((blockIdx.x & 7) << 9) | (blockIdx.x >> 3);
    const int bb  = wid >> 10;
    const int hw  = (wid >> 5) & 31;
    const int wwi = wid & 31;
    const size_t obase = (size_t)bb * 8388608 + (size_t)hw * 2048 + (size_t)wwi * 8;
    float* outw = out + obase;
    const float* w2 = win2tm + (size_t)wid*8192;

    // stage win2 -> bf16 [tok][c] swizzled in H
#pragma unroll
    for (int it = 0; it < 4; ++it) {
        int idx = it*512 + tid;
        int tok = idx >> 5;
        int cg  = idx & 31;
        f32x4 v = *(const f32x4*)(w2 + tok*128 + cg*4);
        uint2 u;
        u.x = packbf(v[0], v[1]);
        u.y = packbf(v[2], v[3]);
        *(uint2*)(sm + tok*256 + ((cg*8) ^ ((tok&7)<<4))) = u;
    }
    __syncthreads();

    // LN2 in place
    {
        const int t = tid >> 3, p = tid & 7;
        const int swz = (t & 7) << 4;
        float vv[16];
        float s = 0.f, s2 = 0.f;
#pragma unroll
        for (int hlf = 0; hlf < 2; ++hlf) {
            bf16x8 xv = *(const bf16x8*)(sm + t*256 + ((p*32 + hlf*16) ^ swz));
#pragma unroll
            for (int e = 0; e < 8; ++e) { float f = (float)xv[e]; vv[hlf*8+e] = f; s += f; s2 += f*f; }
        }
#pragma unroll
        for (int m = 1; m < 8; m <<= 1) { s += __shfl_xor(s, m, 64); s2 += __shfl_xor(s2, m, 64); }
        const float mean = s * 0.0078125f;
        const float rs = rsqrtf(s2 * 0.0078125f - mean*mean + 1e-5f);
#pragma unroll
        for (int hlf = 0; hlf < 2; ++hlf) {
            bf16x8 hv;
#pragma unroll
            for (int e = 0; e < 8; ++e) {
                int c = p*16 + hlf*8 + e;
                hv[e] = (bf16)((vv[hlf*8+e] - mean) * rs * ln2_g[c] + ln2_b[c]);
            }
            *(bf16x8*)(sm + t*256 + ((p*32 + hlf*16) ^ swz)) = hv;
        }
    }
    __syncthreads();

    // MLP: ping-pong g; fc1(c4+1) issued before fc2(c4) each iteration
    f32x4 acc2[4];
#pragma unroll
    for (int nt = 0; nt < 4; ++nt) acc2[nt] = zero4();

    mlp_fc1_chunk(sm, sm + 16384, wfc1T, b_fc1, 0, fmt, fn0, l15, l4);
#pragma unroll
    for (int c4 = 0; c4 < 4; ++c4) {
        __syncthreads();                                  // g[c4&1] ready for all waves
        if (c4 < 3)
            mlp_fc1_chunk(sm, sm + 16384 + (((c4+1)&1) << 14), wfc1T, b_fc1,
                          c4+1, fmt, fn0, l15, l4);       // overlaps fc2 below
        const char* gcur = sm + 16384 + ((c4&1) << 14);
#pragma unroll
        for (int ks = 0; ks < 4; ++ks) {
            int tok = fmt*16 + l15;
            bf16x8 afr = *(const bf16x8*)(gcur + tok*256 + ((ks*64 + l4*16) ^ ((tok&7)<<4)));
#pragma unroll
            for (int nt = 0; nt < 4; ++nt) {
                int n = fn0 + nt*16 + l15;
                bf16x8 bfr = *(const bf16x8*)(wfc2T + n*512 + c4*128 + ks*32 + l4*8);
                acc2[nt] = MFMA16(afr, bfr, acc2[nt]);
            }
        }
    }
    // last reads of [0:32K) happened before the c4=3 barrier -> safe to dump now

    // residual (re-read win2 f32) + dump f32 + BCHW writeback
    {
#pragma unroll
        for (int nt = 0; nt < 4; ++nt) {
            int c = fn0 + nt*16 + l15;
            float bf_ = b_fc2[c];
#pragma unroll
            for (int r = 0; r < 4; ++r) {
                int tok = fmt*16 + l4*4 + r;
                float res = w2[tok*128 + c];
                *(float*)(sm + tok*512 + ((c*4) ^ ((tok&15)<<4))) = res + acc2[nt][r] + bf_;
            }
        }
    }
    __syncthreads();
#pragma unroll
    for (int it = 0; it < 4; ++it) {
        int idx = it*512 + tid;
        int c = idx >> 4, t2 = idx & 15;
        int row = t2 >> 1, col0 = (t2 & 1) * 4;
        f32x4 v;
#pragma unroll
        for (int e = 0; e < 4; ++e) {
            int t = row*8 + col0 + e;
            v[e] = *(const float*)(sm + t*512 + ((c*4) ^ ((t&15)<<4)));
        }
        *(f32x4*)(outw + (size_t)c*65536 + row*256 + col0) = v;
    }
}

// ---------------------------------------------------------------------------
// fallback: R9 monolithic fused kernel (used if ws too small for win2tm)
// ---------------------------------------------------------------------------
__global__ __launch_bounds__(512, 4) void swin_fused(
    const float* __restrict__ x,
    const float* __restrict__ ln1_g, const float* __restrict__ ln1_b,
    const float* __restrict__ b_qkv, const float* __restrict__ b_proj,
    const float* __restrict__ ln2_g, const float* __restrict__ ln2_b,
    const float* __restrict__ b_fc1, const float* __restrict__ b_fc2,
    const bf16* __restrict__ wqkvT, const bf16* __restrict__ wprojT,
    const bf16* __restrict__ wfc1T, const bf16* __restrict__ wfc2T,
    const float* __restrict__ bN,
    float* __restrict__ out)
{
    __shared__ __align__(16) char sm[49152];

    const int tid  = threadIdx.x;
    const int lane = tid & 63;
    const int wv   = tid >> 6;
    const int l15  = lane & 15;
    const int l4   = (lane >> 4) & 3;
    const int l31  = lane & 31;
    const int hi   = lane >> 5;
    const int fmt  = wv >> 1;
    const int fn0  = (wv & 1) * 64;

    const int wid = ((blockIdx.x & 7) << 9) | (blockIdx.x >> 3);
    const int bb  = wid >> 10;
    const int hw  = (wid >> 5) & 31;
    const int wwi = wid & 31;
    const size_t base = (size_t)bb * 8388608 + (size_t)hw * 2048 + (size_t)wwi * 8;
    const float* xw   = x   + base;
    float*       outw = out + base;

#pragma unroll
    for (int it = 0; it < 4; ++it) {
        int idx = it*512 + tid;
        int c = idx >> 4, t2 = idx & 15;
        int row = t2 >> 1, col0 = (t2 & 1) * 4;
        f32x4 v = *(const f32x4*)(xw + (size_t)c*65536 + row*256 + col0);
#pragma unroll
        for (int e = 0; e < 4; ++e) {
            int t = row*8 + col0 + e;
            *(bf16*)(sm + t*256 + ((2*c) ^ ((t&7)<<4))) = (bf16)v[e];
        }
    }
    __syncthreads();

    uint32_t winp[2][4];
#pragma unroll
    for (int r = 0; r < 4; ++r) {
        int tok = fmt*16 + l4*4 + r;
        int swz = (tok & 7) << 4;
        const char* rowp = sm + tok*256;
        uint32_t c0 = *(const uint16_t*)(rowp + ((2*(fn0 +  0 + l15)) ^ swz));
        uint32_t c1 = *(const uint16_t*)(rowp + ((2*(fn0 + 16 + l15)) ^ swz));
        uint32_t c2 = *(const uint16_t*)(rowp + ((2*(fn0 + 32 + l15)) ^ swz));
        uint32_t c3 = *(const uint16_t*)(rowp + ((2*(fn0 + 48 + l15)) ^ swz));
        winp[0][r] = c0 | (c1 << 16);
        winp[1][r] = c2 | (c3 << 16);
    }

    {
        const int t = tid >> 3, p = tid & 7;
        const int swz = (t & 7) << 4;
        float vv[16];
        float s = 0.f, s2 = 0.f;
#pragma unroll
        for (int hlf = 0; hlf < 2; ++hlf) {
            bf16x8 xv = *(const bf16x8*)(sm + t*256 + ((p*32 + hlf*16) ^ swz));
#pragma unroll
            for (int e = 0; e < 8; ++e) { float f = (float)xv[e]; vv[hlf*8+e] = f; s += f; s2 += f*f; }
        }
#pragma unroll
        for (int m = 1; m < 8; m <<= 1) { s += __shfl_xor(s, m, 64); s2 += __shfl_xor(s2, m, 64); }
        const float mean = s * 0.0078125f;
        const float rs = rsqrtf(s2 * 0.0078125f - mean*mean + 1e-5f);
#pragma unroll
        for (int hlf = 0; hlf < 2; ++hlf) {
            bf16x8 hv;
#pragma unroll
            for (int e = 0; e < 8; ++e) {
                int c = p*16 + hlf*8 + e;
                hv[e] = (bf16)((vv[hlf*8+e] - mean) * rs * ln1_g[c] + ln1_b[c]);
            }
            *(bf16x8*)(sm + 16384 + t*256 + ((p*32 + hlf*16) ^ swz)) = hv;
        }
    }
    __syncthreads();

    {
        const float SCALE = 0.35355339059327373f;
        const int nq0 = wv * 32;
        const int nv  = 256 + wv*16 + l15;
        const float bb0 = b_qkv[nq0 + l15];
        const float bb1 = b_qkv[nq0 + 16 + l15];
        const float bbv = b_qkv[nv];
        const bool isq = (nq0 < 128);
        char* rb = isq ? (sm + 16384) : (sm + 32768);
        const float sc = isq ? SCALE : 1.0f;
        const int c0 = (nq0 & 127) + l15;
        const int c1 = ((nq0 + 16) & 127) + l15;
#pragma unroll
        for (int half = 0; half < 2; ++half) {
            f32x4 a0[2], a1[2], avh[2];
#pragma unroll
            for (int m2 = 0; m2 < 2; ++m2) { a0[m2] = zero4(); a1[m2] = zero4(); avh[m2] = zero4(); }
#pragma unroll
            for (int ks = 0; ks < 4; ++ks) {
                bf16x8 bq0 = *(const bf16x8*)(wqkvT + (nq0      + l15)*128 + ks*32 + l4*8);
                bf16x8 bq1 = *(const bf16x8*)(wqkvT + (nq0 + 16 + l15)*128 + ks*32 + l4*8);
                bf16x8 bv  = *(const bf16x8*)(wqkvT + nv*128 + ks*32 + l4*8);
#pragma unroll
                for (int m2 = 0; m2 < 2; ++m2) {
                    int tok = half*32 + m2*16 + l15;
                    bf16x8 afr = *(const bf16x8*)(sm + 16384 + tok*256 + ((ks*64 + l4*16) ^ ((tok&7)<<4)));
                    a0[m2]  = MFMA16(afr, bq0, a0[m2]);
                    a1[m2]  = MFMA16(afr, bq1, a1[m2]);
                    avh[m2] = MFMA16(afr, bv,  avh[m2]);
                }
            }
            __syncthreads();
#pragma unroll
            for (int m2 = 0; m2 < 2; ++m2)
#pragma unroll
                for (int r = 0; r < 4; ++r) {
                    int tok = half*32 + m2*16 + l4*4 + r;
                    int swz = (tok & 7) << 4;
                    *(bf16*)(rb + tok*256 + ((2*c0) ^ swz)) = (bf16)((a0[m2][r] + bb0) * sc);
                    *(bf16*)(rb + tok*256 + ((2*c1) ^ swz)) = (bf16)((a1[m2][r] + bb1) * sc);
                }
            {
                int d = l15;
                char* vb = sm + wv*2048 + d*128;
                int sz = (d & 7) << 4;
#pragma unroll
                for (int m2 = 0; m2 < 2; ++m2) {
                    int t0 = half*32 + m2*16 + l4*4;
                    *(uint32_t*)(vb + ((2*t0)     ^ sz)) = packbf(avh[m2][0]+bbv, avh[m2][1]+bbv);
                    *(uint32_t*)(vb + ((2*t0 + 4) ^ sz)) = packbf(avh[m2][2]+bbv, avh[m2][3]+bbv);
                }
            }
        }
    }
    __syncthreads();

    {
        bf16x8 kf[2];
#pragma unroll
        for (int tk = 0; tk < 2; ++tk) {
            int tok = tk*32 + l31;
            kf[tk] = *(const bf16x8*)(sm + 32768 + tok*256 + ((wv*32 + hi*16) ^ ((tok&7)<<4)));
        }
        __syncthreads();
#pragma unroll
        for (int tq = 0; tq < 2; ++tq) {
            int q = tq*32 + l31;
            bf16x8 qf = *(const bf16x8*)(sm + 16384 + q*256 + ((wv*32 + hi*16) ^ ((q&7)<<4)));
            const float* bq = bN + wv*4096 + q*64 + 4*hi;
            float ss, ri;
            uint32_t own[16];
            {
                f32x16 s0, s1;
#pragma unroll
                for (int g4 = 0; g4 < 4; ++g4) {
                    f32x4 b0 = *(const f32x4*)(bq + g4*8);
                    f32x4 b1 = *(const f32x4*)(bq + 32 + g4*8);
#pragma unroll
                    for (int e = 0; e < 4; ++e) { s0[g4*4+e] = b0[e]; s1[g4*4+e] = b1[e]; }
                }
                s0 = MFMA32(kf[0], qf, s0);
                s1 = MFMA32(kf[1], qf, s1);
                ss = 0.f;
#pragma unroll
                for (int r = 0; r < 16; ++r) {
                    s0[r] = __expf(s0[r]);
                    s1[r] = __expf(s1[r]);
                    ss += s0[r] + s1[r];
                }
#pragma unroll
                for (int ks = 0; ks < 4; ++ks)
#pragma unroll
                    for (int i = 0; i < 4; ++i) {
                        const int j = 2*(i&1) + 4*((2*ks + (i>>1)) & 3) + 16*(ks>>1);
                        if (j < 16) own[ks*4+i] = packbf(s0[j], s0[j+1]);
                        else        own[ks*4+i] = packbf(s1[j-16], s1[j-15]);
                    }
            }
            ss += __shfl_xor(ss, 32, 64);
            ri = 1.0f / ss;
            f32x16 Ot;
#pragma unroll
            for (int i = 0; i < 16; ++i) Ot[i] = 0.f;
#pragma unroll
            for (int ks = 0; ks < 4; ++ks) {
                uint32_t sw0 = __shfl_xor(own[ks*4+0], 32, 64);
                uint32_t sw1 = __shfl_xor(own[ks*4+1], 32, 64);
                uint32_t sw2 = __shfl_xor(own[ks*4+2], 32, 64);
                uint32_t sw3 = __shfl_xor(own[ks*4+3], 32, 64);
                uint32_t w0 = hi ? sw2          : own[ks*4+0];
                uint32_t w1 = hi ? sw3          : own[ks*4+1];
                uint32_t w2 = hi ? own[ks*4+2]  : sw0;
                uint32_t w3 = hi ? own[ks*4+3]  : sw1;
                bf16x8 pf = frag_from_words(w0, w1, w2, w3);
                int dd = l31 & 15;
                bf16x8 vf = *(const bf16x8*)(sm + wv*2048 + dd*128
                                             + ((ks*32 + hi*16) ^ ((dd&7)<<4)));
                Ot = MFMA32(vf, pf, Ot);
            }
#pragma unroll
            for (int r = 0; r < 8; r += 2) {
                int d = (r&3) + 8*(r>>2) + 4*hi;
                *(uint32_t*)(sm + 32768 + q*256 + ((2*(wv*16 + d)) ^ ((q&7)<<4)))
                    = packbf(Ot[r]*ri, Ot[r+1]*ri);
            }
        }
    }
    __syncthreads();

    float win2[4][4];
    {
        f32x4 acc[4];
#pragma unroll
        for (int nt = 0; nt < 4; ++nt) acc[nt] = zero4();
#pragma unroll
        for (int ks = 0; ks < 4; ++ks) {
            int tok = fmt*16 + l15;
            bf16x8 afr = *(const bf16x8*)(sm + 32768 + tok*256 + ((ks*64 + l4*16) ^ ((tok&7)<<4)));
#pragma unroll
            for (int nt = 0; nt < 4; ++nt) {
                int n = fn0 + nt*16 + l15;
                bf16x8 bfr = *(const bf16x8*)(wprojT + n*128 + ks*32 + l4*8);
                acc[nt] = MFMA16(afr, bfr, acc[nt]);
            }
        }
#pragma unroll
        for (int nt = 0; nt < 4; ++nt) {
            float bp = b_proj[fn0 + nt*16 + l15];
#pragma unroll
            for (int r = 0; r < 4; ++r) {
                uint32_t w = winp[nt >> 1][r];
                float xr = uf((nt & 1) ? (w & 0xffff0000u) : (w << 16));
                win2[nt][r] = xr + acc[nt][r] + bp;
            }
        }
    }

    {
        float s[4], s2[4];
#pragma unroll
        for (int r = 0; r < 4; ++r) {
            s[r]  = win2[0][r] + win2[1][r] + win2[2][r] + win2[3][r];
            s2[r] = win2[0][r]*win2[0][r] + win2[1][r]*win2[1][r]
                  + win2[2][r]*win2[2][r] + win2[3][r]*win2[3][r];
#pragma unroll
            for (int m = 1; m < 16; m <<= 1) {
                s[r]  += __shfl_xor(s[r],  m, 64);
                s2[r] += __shfl_xor(s2[r], m, 64);
            }
        }
        float2* scr = (float2*)sm;
        if (l15 == 0) {
#pragma unroll
            for (int r = 0; r < 4; ++r) {
                int tok = fmt*16 + l4*4 + r;
                scr[tok*2 + (wv&1)] = make_float2(s[r], s2[r]);
            }
        }
        __syncthreads();
        float mean[4], rstd[4];
#pragma unroll
        for (int r = 0; r < 4; ++r) {
            int tok = fmt*16 + l4*4 + r;
            float2 p = scr[tok*2 + ((wv&1)^1)];
            float tot = s[r] + p.x, tot2 = s2[r] + p.y;
            float m = tot * 0.0078125f;
            mean[r] = m;
            rstd[r] = rsqrtf(tot2*0.0078125f - m*m + 1e-5f);
        }
#pragma unroll
        for (int nt = 0; nt < 4; ++nt) {
            int c = fn0 + nt*16 + l15;
            float gg = ln2_g[c], bb2 = ln2_b[c];
#pragma unroll
            for (int r = 0; r < 4; ++r) {
                int tok = fmt*16 + l4*4 + r;
                *(bf16*)(sm + 16384 + tok*256 + ((2*c) ^ ((tok&7)<<4)))
                    = (bf16)((win2[nt][r] - mean[r]) * rstd[r] * gg + bb2);
            }
        }
    }
    __syncthreads();

    {
        f32x4 acc2[4];
#pragma unroll
        for (int nt = 0; nt < 4; ++nt) acc2[nt] = zero4();
#pragma unroll
        for (int c4 = 0; c4 < 4; ++c4) {
            char* gbuf = (c4 & 1) ? (sm + 32768) : sm;
            {
                f32x4 a1[4];
#pragma unroll
                for (int nt = 0; nt < 4; ++nt) a1[nt] = zero4();
#pragma unroll
                for (int ks = 0; ks < 4; ++ks) {
                    int tok = fmt*16 + l15;
                    bf16x8 afr = *(const bf16x8*)(sm + 16384 + tok*256 + ((ks*64 + l4*16) ^ ((tok&7)<<4)));
#pragma unroll
                    for (int nt = 0; nt < 4; ++nt) {
                        int n = c4*128 + fn0 + nt*16 + l15;
                        bf16x8 bfr = *(const bf16x8*)(wfc1T + n*128 + ks*32 + l4*8);
                        a1[nt] = MFMA16(afr, bfr, a1[nt]);
                    }
                }
#pragma unroll
                for (int nt = 0; nt < 4; ++nt) {
                    int cl = fn0 + nt*16 + l15;
                    float b1 = b_fc1[c4*128 + cl];
#pragma unroll
                    for (int r = 0; r < 4; ++r) {
                        int tok = fmt*16 + l4*4 + r;
                        float u = a1[nt][r] + b1;
                        *(bf16*)(gbuf + tok*256 + ((2*cl) ^ ((tok&7)<<4))) = (bf16)gelu_f(u);
                    }
                }
            }
            __syncthreads();
#pragma unroll
            for (int ks = 0; ks < 4; ++ks) {
                int tok = fmt*16 + l15;
                bf16x8 afr = *(const bf16x8*)(gbuf + tok*256 + ((ks*64 + l4*16) ^ ((tok&7)<<4)));
#pragma unroll
                for (int nt = 0; nt < 4; ++nt) {
                    int n = fn0 + nt*16 + l15;
                    bf16x8 bfr = *(const bf16x8*)(wfc2T + n*512 + c4*128 + ks*32 + l4*8);
                    acc2[nt] = MFMA16(afr, bfr, acc2[nt]);
                }
            }
        }
#pragma unroll
        for (int nt = 0; nt < 4; ++nt) {
            float bf_ = b_fc2[fn0 + nt*16 + l15];
#pragma unroll
            for (int r = 0; r < 4; ++r) win2[nt][r] += acc2[nt][r] + bf_;
        }
    }
    __syncthreads();

#pragma unroll
    for (int nt = 0; nt < 4; ++nt)
#pragma unroll
        for (int r = 0; r < 4; ++r) {
            int tok = fmt*16 + l4*4 + r;
            int c   = fn0 + nt*16 + l15;
            *(float*)(sm + tok*512 + ((c*4) ^ ((tok&15)<<4))) = win2[nt][r];
        }
    __syncthreads();
#pragma unroll
    for (int it = 0; it < 4; ++it) {
        int idx = it*512 + tid;
        int c = idx >> 4, t2 = idx & 15;
        int row = t2 >> 1, col0 = (t2 & 1) * 4;
        f32x4 v;
#pragma unroll
        for (int e = 0; e < 4; ++e) {
            int t = row*8 + col0 + e;
            v[e] = *(const float*)(sm + t*512 + ((c*4) ^ ((t&15)<<4)));
        }
        *(f32x4*)(outw + (size_t)c*65536 + row*256 + col0) = v;
    }
}

extern "C" void kernel_launch(void* const* d_in, const int* in_sizes, int n_in,
                              void* d_out, int out_size, void* d_ws, size_t ws_size,
                              hipStream_t stream) {
    const float* x      = (const float*)d_in[0];
    const float* ln1_g  = (const float*)d_in[1];
    const float* ln1_b  = (const float*)d_in[2];
    const float* w_qkv  = (const float*)d_in[3];
    const float* b_qkv  = (const float*)d_in[4];
    const float* w_proj = (const float*)d_in[5];
    const float* b_proj = (const float*)d_in[6];
    const float* btab   = (const float*)d_in[7];
    const float* ln2_g  = (const float*)d_in[8];
    const float* ln2_b  = (const float*)d_in[9];
    const float* w_fc1  = (const float*)d_in[10];
    const float* b_fc1  = (const float*)d_in[11];
    const float* w_fc2  = (const float*)d_in[12];
    const float* b_fc2  = (const float*)d_in[13];
    const int*   relix  = (const int*)d_in[14];
    float* out = (float*)d_out;

    char* ws = (char*)d_ws;
    bf16*  wqkvT  = (bf16*)(ws);
    bf16*  wprojT = (bf16*)(ws + 98304);
    bf16*  wfc1T  = (bf16*)(ws + 131072);
    bf16*  wfc2T  = (bf16*)(ws + 262144);
    float* bN     = (float*)(ws + 393216);
    float* win2tm = (float*)(ws + 524288);

    prep_kernel<<<dim3(448), dim3(512), 0, stream>>>(
        w_qkv, w_proj, w_fc1, w_fc2, btab, relix,
        wqkvT, wprojT, wfc1T, wfc2T, bN);

    const size_t need = 524288ull + 134217728ull;
    if (ws_size >= need) {
        swin_attn<<<dim3(4096), dim3(512), 0, stream>>>(
            x, ln1_g, ln1_b, b_qkv, b_proj, wqkvT, wprojT, bN, win2tm);
        swin_mlp<<<dim3(4096), dim3(512), 0, stream>>>(
            win2tm, ln2_g, ln2_b, b_fc1, b_fc2, wfc1T, wfc2T, out);
    } else {
        swin_fused<<<dim3(4096), dim3(512), 0, stream>>>(
            x, ln1_g, ln1_b, b_qkv, b_proj, ln2_g, ln2_b, b_fc1, b_fc2,
            wqkvT, wprojT, wfc1T, wfc2T, bN, out);
    }
}

// Round 12
// 464.044 us; speedup vs baseline: 1.7002x; 1.6399x over previous
//
#include <hip/hip_runtime.h>
#include <hip/hip_bf16.h>
#include <stdint.h>

typedef __bf16 bf16;
typedef __bf16 bf16x8 __attribute__((ext_vector_type(8)));
typedef float  f32x4  __attribute__((ext_vector_type(4)));
typedef float  f32x16 __attribute__((ext_vector_type(16)));

#define MFMA16(a,b,c) __builtin_amdgcn_mfma_f32_16x16x32_bf16(a,b,c,0,0,0)
#define MFMA32(a,b,c) __builtin_amdgcn_mfma_f32_32x32x16_bf16(a,b,c,0,0,0)

__device__ __forceinline__ f32x4 zero4() { f32x4 z; z[0]=0.f; z[1]=0.f; z[2]=0.f; z[3]=0.f; return z; }

__device__ __forceinline__ uint32_t packbf(float lo, float hi) {
    union { bf16 b[2]; uint32_t u; } t;
    t.b[0] = (bf16)lo; t.b[1] = (bf16)hi;
    return t.u;
}
__device__ __forceinline__ bf16x8 frag_from_words(uint32_t w0, uint32_t w1, uint32_t w2, uint32_t w3) {
    union { uint32_t u[4]; bf16x8 v; } t;
    t.u[0] = w0; t.u[1] = w1; t.u[2] = w2; t.u[3] = w3;
    return t.v;
}
__device__ __forceinline__ float uf(uint32_t u) {
    union { uint32_t u; float f; } t; t.u = u; return t.f;
}
// fast GELU (tanh form, max err ~3e-3)
__device__ __forceinline__ float gelu_f(float u) {
    float u2 = u * u;
    float y  = u * (0.7978845608f + 0.0356774081f * u2);
    float e  = __expf(2.0f * y);
    float t  = 1.0f - 2.0f / (e + 1.0f);
    return 0.5f * u * (1.0f + t);
}

// ---------------------------------------------------------------------------
// prep: weights f32 -> bf16 [n][k]; bias matrix natural: bN[h][q][k]
// ws layout (bytes):
//   0      : wqkvT  [384][128] bf16   (98304)
//   98304  : wprojT [128][128] bf16   (32768)
//   131072 : wfc1T  [512][128] bf16   (131072)
//   262144 : wfc2T  [128][512] bf16   (131072)
//   393216 : bN     [8][64][64] f32   (131072)
//   524288 : win2tm [4096][64][128] f32 (134217728)   [split path only]
// ---------------------------------------------------------------------------
__global__ __launch_bounds__(512) void prep_kernel(
    const float* __restrict__ wqkv, const float* __restrict__ wproj,
    const float* __restrict__ wfc1, const float* __restrict__ wfc2,
    const float* __restrict__ btab, const int* __restrict__ relidx,
    bf16* __restrict__ wqkvT, bf16* __restrict__ wprojT,
    bf16* __restrict__ wfc1T, bf16* __restrict__ wfc2T,
    float* __restrict__ bN)
{
    int i = blockIdx.x * 512 + threadIdx.x;
    if (i < 49152) { int n = i >> 7, k = i & 127; wqkvT[i] = (bf16)wqkv[k*384 + n]; return; }
    i -= 49152;
    if (i < 16384) { int n = i >> 7, k = i & 127; wprojT[i] = (bf16)wproj[k*128 + n]; return; }
    i -= 16384;
    if (i < 65536) { int n = i >> 7, k = i & 127; wfc1T[i] = (bf16)wfc1[k*512 + n]; return; }
    i -= 65536;
    if (i < 65536) { int n = i >> 9, k = i & 511; wfc2T[i] = (bf16)wfc2[k*128 + n]; return; }
    i -= 65536;
    if (i < 32768) { int h = i >> 12, q = (i >> 6) & 63, k = i & 63;
                     bN[i] = btab[relidx[q*64 + k]*8 + h]; }
}

// ---------------------------------------------------------------------------
// kernel1: x -> LN1 -> QKV -> attention -> proj + residual -> win2 (token-major f32)
// (identical to R10/R11)
// ---------------------------------------------------------------------------
__global__ __launch_bounds__(512, 4) void swin_attn(
    const float* __restrict__ x,
    const float* __restrict__ ln1_g, const float* __restrict__ ln1_b,
    const float* __restrict__ b_qkv, const float* __restrict__ b_proj,
    const bf16* __restrict__ wqkvT, const bf16* __restrict__ wprojT,
    const float* __restrict__ bN,
    float* __restrict__ win2tm)
{
    __shared__ __align__(16) char sm[49152];

    const int tid  = threadIdx.x;
    const int lane = tid & 63;
    const int wv   = tid >> 6;
    const int l15  = lane & 15;
    const int l4   = (lane >> 4) & 3;
    const int l31  = lane & 31;
    const int hi   = lane >> 5;
    const int fmt  = wv >> 1;
    const int fn0  = (wv & 1) * 64;

    const int wid = ((blockIdx.x & 7) << 9) | (blockIdx.x >> 3);
    const int bb  = wid >> 10;
    const int hw  = (wid >> 5) & 31;
    const int wwi = wid & 31;
    const size_t base = (size_t)bb * 8388608 + (size_t)hw * 2048 + (size_t)wwi * 8;
    const float* xw = x + base;

#pragma unroll
    for (int it = 0; it < 4; ++it) {
        int idx = it*512 + tid;
        int c = idx >> 4, t2 = idx & 15;
        int row = t2 >> 1, col0 = (t2 & 1) * 4;
        f32x4 v = *(const f32x4*)(xw + (size_t)c*65536 + row*256 + col0);
#pragma unroll
        for (int e = 0; e < 4; ++e) {
            int t = row*8 + col0 + e;
            *(bf16*)(sm + t*256 + ((2*c) ^ ((t&7)<<4))) = (bf16)v[e];
        }
    }
    __syncthreads();   // B1

    uint32_t winp[2][4];
#pragma unroll
    for (int r = 0; r < 4; ++r) {
        int tok = fmt*16 + l4*4 + r;
        int swz = (tok & 7) << 4;
        const char* rowp = sm + tok*256;
        uint32_t c0 = *(const uint16_t*)(rowp + ((2*(fn0 +  0 + l15)) ^ swz));
        uint32_t c1 = *(const uint16_t*)(rowp + ((2*(fn0 + 16 + l15)) ^ swz));
        uint32_t c2 = *(const uint16_t*)(rowp + ((2*(fn0 + 32 + l15)) ^ swz));
        uint32_t c3 = *(const uint16_t*)(rowp + ((2*(fn0 + 48 + l15)) ^ swz));
        winp[0][r] = c0 | (c1 << 16);
        winp[1][r] = c2 | (c3 << 16);
    }

    {
        const int t = tid >> 3, p = tid & 7;
        const int swz = (t & 7) << 4;
        float vv[16];
        float s = 0.f, s2 = 0.f;
#pragma unroll
        for (int hlf = 0; hlf < 2; ++hlf) {
            bf16x8 xv = *(const bf16x8*)(sm + t*256 + ((p*32 + hlf*16) ^ swz));
#pragma unroll
            for (int e = 0; e < 8; ++e) { float f = (float)xv[e]; vv[hlf*8+e] = f; s += f; s2 += f*f; }
        }
#pragma unroll
        for (int m = 1; m < 8; m <<= 1) { s += __shfl_xor(s, m, 64); s2 += __shfl_xor(s2, m, 64); }
        const float mean = s * 0.0078125f;
        const float rs = rsqrtf(s2 * 0.0078125f - mean*mean + 1e-5f);
#pragma unroll
        for (int hlf = 0; hlf < 2; ++hlf) {
            bf16x8 hv;
#pragma unroll
            for (int e = 0; e < 8; ++e) {
                int c = p*16 + hlf*8 + e;
                hv[e] = (bf16)((vv[hlf*8+e] - mean) * rs * ln1_g[c] + ln1_b[c]);
            }
            *(bf16x8*)(sm + 16384 + t*256 + ((p*32 + hlf*16) ^ swz)) = hv;
        }
    }
    __syncthreads();   // B2

    {
        const float SCALE = 0.35355339059327373f;
        const int nq0 = wv * 32;
        const int nv  = 256 + wv*16 + l15;
        const float bb0 = b_qkv[nq0 + l15];
        const float bb1 = b_qkv[nq0 + 16 + l15];
        const float bbv = b_qkv[nv];
        const bool isq = (nq0 < 128);
        char* rb = isq ? (sm + 16384) : (sm + 32768);
        const float sc = isq ? SCALE : 1.0f;
        const int c0 = (nq0 & 127) + l15;
        const int c1 = ((nq0 + 16) & 127) + l15;
#pragma unroll
        for (int half = 0; half < 2; ++half) {
            f32x4 a0[2], a1[2], avh[2];
#pragma unroll
            for (int m2 = 0; m2 < 2; ++m2) { a0[m2] = zero4(); a1[m2] = zero4(); avh[m2] = zero4(); }
#pragma unroll
            for (int ks = 0; ks < 4; ++ks) {
                bf16x8 bq0 = *(const bf16x8*)(wqkvT + (nq0      + l15)*128 + ks*32 + l4*8);
                bf16x8 bq1 = *(const bf16x8*)(wqkvT + (nq0 + 16 + l15)*128 + ks*32 + l4*8);
                bf16x8 bv  = *(const bf16x8*)(wqkvT + nv*128 + ks*32 + l4*8);
#pragma unroll
                for (int m2 = 0; m2 < 2; ++m2) {
                    int tok = half*32 + m2*16 + l15;
                    bf16x8 afr = *(const bf16x8*)(sm + 16384 + tok*256 + ((ks*64 + l4*16) ^ ((tok&7)<<4)));
                    a0[m2]  = MFMA16(afr, bq0, a0[m2]);
                    a1[m2]  = MFMA16(afr, bq1, a1[m2]);
                    avh[m2] = MFMA16(afr, bv,  avh[m2]);
                }
            }
            __syncthreads();   // B3a / B3b
#pragma unroll
            for (int m2 = 0; m2 < 2; ++m2)
#pragma unroll
                for (int r = 0; r < 4; ++r) {
                    int tok = half*32 + m2*16 + l4*4 + r;
                    int swz = (tok & 7) << 4;
                    *(bf16*)(rb + tok*256 + ((2*c0) ^ swz)) = (bf16)((a0[m2][r] + bb0) * sc);
                    *(bf16*)(rb + tok*256 + ((2*c1) ^ swz)) = (bf16)((a1[m2][r] + bb1) * sc);
                }
            {
                int d = l15;
                char* vb = sm + wv*2048 + d*128;
                int sz = (d & 7) << 4;
#pragma unroll
                for (int m2 = 0; m2 < 2; ++m2) {
                    int t0 = half*32 + m2*16 + l4*4;
                    *(uint32_t*)(vb + ((2*t0)     ^ sz)) = packbf(avh[m2][0]+bbv, avh[m2][1]+bbv);
                    *(uint32_t*)(vb + ((2*t0 + 4) ^ sz)) = packbf(avh[m2][2]+bbv, avh[m2][3]+bbv);
                }
            }
        }
    }
    __syncthreads();   // B3

    {
        bf16x8 kf[2];
#pragma unroll
        for (int tk = 0; tk < 2; ++tk) {
            int tok = tk*32 + l31;
            kf[tk] = *(const bf16x8*)(sm + 32768 + tok*256 + ((wv*32 + hi*16) ^ ((tok&7)<<4)));
        }
        __syncthreads();   // B4
#pragma unroll
        for (int tq = 0; tq < 2; ++tq) {
            int q = tq*32 + l31;
            bf16x8 qf = *(const bf16x8*)(sm + 16384 + q*256 + ((wv*32 + hi*16) ^ ((q&7)<<4)));
            const float* bq = bN + wv*4096 + q*64 + 4*hi;
            float ss, ri;
            uint32_t own[16];
            {
                f32x16 s0, s1;
#pragma unroll
                for (int g4 = 0; g4 < 4; ++g4) {
                    f32x4 b0 = *(const f32x4*)(bq + g4*8);
                    f32x4 b1 = *(const f32x4*)(bq + 32 + g4*8);
#pragma unroll
                    for (int e = 0; e < 4; ++e) { s0[g4*4+e] = b0[e]; s1[g4*4+e] = b1[e]; }
                }
                s0 = MFMA32(kf[0], qf, s0);
                s1 = MFMA32(kf[1], qf, s1);
                ss = 0.f;
#pragma unroll
                for (int r = 0; r < 16; ++r) {
                    s0[r] = __expf(s0[r]);
                    s1[r] = __expf(s1[r]);
                    ss += s0[r] + s1[r];
                }
#pragma unroll
                for (int ks = 0; ks < 4; ++ks)
#pragma unroll
                    for (int i = 0; i < 4; ++i) {
                        const int j = 2*(i&1) + 4*((2*ks + (i>>1)) & 3) + 16*(ks>>1);
                        if (j < 16) own[ks*4+i] = packbf(s0[j], s0[j+1]);
                        else        own[ks*4+i] = packbf(s1[j-16], s1[j-15]);
                    }
            }
            ss += __shfl_xor(ss, 32, 64);
            ri = 1.0f / ss;
            f32x16 Ot;
#pragma unroll
            for (int i = 0; i < 16; ++i) Ot[i] = 0.f;
#pragma unroll
            for (int ks = 0; ks < 4; ++ks) {
                uint32_t sw0 = __shfl_xor(own[ks*4+0], 32, 64);
                uint32_t sw1 = __shfl_xor(own[ks*4+1], 32, 64);
                uint32_t sw2 = __shfl_xor(own[ks*4+2], 32, 64);
                uint32_t sw3 = __shfl_xor(own[ks*4+3], 32, 64);
                uint32_t w0 = hi ? sw2          : own[ks*4+0];
                uint32_t w1 = hi ? sw3          : own[ks*4+1];
                uint32_t w2 = hi ? own[ks*4+2]  : sw0;
                uint32_t w3 = hi ? own[ks*4+3]  : sw1;
                bf16x8 pf = frag_from_words(w0, w1, w2, w3);
                int dd = l31 & 15;
                bf16x8 vf = *(const bf16x8*)(sm + wv*2048 + dd*128
                                             + ((ks*32 + hi*16) ^ ((dd&7)<<4)));
                Ot = MFMA32(vf, pf, Ot);
            }
#pragma unroll
            for (int r = 0; r < 8; r += 2) {
                int d = (r&3) + 8*(r>>2) + 4*hi;
                *(uint32_t*)(sm + 32768 + q*256 + ((2*(wv*16 + d)) ^ ((q&7)<<4)))
                    = packbf(Ot[r]*ri, Ot[r+1]*ri);
            }
        }
    }
    __syncthreads();   // B5

    {
        f32x4 acc[4];
#pragma unroll
        for (int nt = 0; nt < 4; ++nt) acc[nt] = zero4();
#pragma unroll
        for (int ks = 0; ks < 4; ++ks) {
            int tok = fmt*16 + l15;
            bf16x8 afr = *(const bf16x8*)(sm + 32768 + tok*256 + ((ks*64 + l4*16) ^ ((tok&7)<<4)));
#pragma unroll
            for (int nt = 0; nt < 4; ++nt) {
                int n = fn0 + nt*16 + l15;
                bf16x8 bfr = *(const bf16x8*)(wprojT + n*128 + ks*32 + l4*8);
                acc[nt] = MFMA16(afr, bfr, acc[nt]);
            }
        }
        float* w2 = win2tm + (size_t)wid*8192;
#pragma unroll
        for (int nt = 0; nt < 4; ++nt) {
            int c = fn0 + nt*16 + l15;
            float bp = b_proj[c];
#pragma unroll
            for (int r = 0; r < 4; ++r) {
                int tok = fmt*16 + l4*4 + r;
                uint32_t w = winp[nt >> 1][r];
                float xr = uf((nt & 1) ? (w & 0xffff0000u) : (w << 16));
                w2[tok*128 + c] = xr + acc[nt][r] + bp;
            }
        }
    }
}

// ---------------------------------------------------------------------------
// kernel2 (column-sliced): win2 -> LN2 (direct from global) -> MLP -> out BCHW
// wave wv owns cols [wv*16, wv*16+16) of every fc1 chunk AND of the fc2 output
// -> zero weight-read redundancy (8 KB/wave/chunk vs 32 KB), a1 = 4 tiles.
// LDS 49152 = H[0:16K) h2 | gA[16K:32K) | gB[32K:48K); dump reuses [0:32K).
// ---------------------------------------------------------------------------
__global__ __launch_bounds__(512, 4) void swin_mlp(
    const float* __restrict__ win2tm,
    const float* __restrict__ ln2_g, const float* __restrict__ ln2_b,
    const float* __restrict__ b_fc1, const float* __restrict__ b_fc2,
    const bf16* __restrict__ wfc1T, const bf16* __restrict__ wfc2T,
    float* __restrict__ out)
{
    __shared__ __align__(16) char sm[49152];

    const int tid  = threadIdx.x;
    const int lane = tid & 63;
    const int wv   = tid >> 6;
    const int l15  = lane & 15;
    const int l4   = (lane >> 4) & 3;
    const int cw   = wv * 16 + l15;     // this thread's output column (fc1-chunk-local & fc2)

    const int wid = ((blockIdx.x & 7) << 9) | (blockIdx.x >> 3);
    const int bb  = wid >> 10;
    const int hw  = (wid >> 5) & 31;
    const int wwi = wid & 31;
    const size_t obase = (size_t)bb * 8388608 + (size_t)hw * 2048 + (size_t)wwi * 8;
    float* outw = out + obase;
    const float* w2 = win2tm + (size_t)wid*8192;

    // LN2 straight from global into H (bf16, swizzled) — no LDS staging pass
    {
        const int t = tid >> 3, p = tid & 7;
        const int swz = (t & 7) << 4;
        float vv[16];
        float s = 0.f, s2 = 0.f;
#pragma unroll
        for (int i4 = 0; i4 < 4; ++i4) {
            f32x4 v = *(const f32x4*)(w2 + t*128 + p*16 + i4*4);
#pragma unroll
            for (int e = 0; e < 4; ++e) { float f = v[e]; vv[i4*4+e] = f; s += f; s2 += f*f; }
        }
#pragma unroll
        for (int m = 1; m < 8; m <<= 1) { s += __shfl_xor(s, m, 64); s2 += __shfl_xor(s2, m, 64); }
        const float mean = s * 0.0078125f;
        const float rs = rsqrtf(s2 * 0.0078125f - mean*mean + 1e-5f);
#pragma unroll
        for (int hlf = 0; hlf < 2; ++hlf) {
            bf16x8 hv;
#pragma unroll
            for (int e = 0; e < 8; ++e) {
                int c = p*16 + hlf*8 + e;
                hv[e] = (bf16)((vv[hlf*8+e] - mean) * rs * ln2_g[c] + ln2_b[c]);
            }
            *(bf16x8*)(sm + t*256 + ((p*32 + hlf*16) ^ swz)) = hv;
        }
    }
    __syncthreads();

    f32x4 acc2[4];
#pragma unroll
    for (int mt = 0; mt < 4; ++mt) acc2[mt] = zero4();

    // fc1 chunk (column-sliced): 4 weight loads, each reused by 4 MFMAs
#define FC1_CHUNK(C4, GB)                                                          \
    {                                                                              \
        f32x4 a1[4];                                                               \
        a1[0] = zero4(); a1[1] = zero4(); a1[2] = zero4(); a1[3] = zero4();        \
        _Pragma("unroll")                                                          \
        for (int ks = 0; ks < 4; ++ks) {                                           \
            bf16x8 bfr = *(const bf16x8*)(wfc1T + ((C4)*128 + cw)*128 + ks*32 + l4*8); \
            _Pragma("unroll")                                                      \
            for (int mt = 0; mt < 4; ++mt) {                                       \
                int tok = mt*16 + l15;                                             \
                bf16x8 afr = *(const bf16x8*)(sm + tok*256 + ((ks*64 + l4*16) ^ ((tok&7)<<4))); \
                a1[mt] = MFMA16(afr, bfr, a1[mt]);                                 \
            }                                                                      \
        }                                                                          \
        float b1 = b_fc1[(C4)*128 + cw];                                           \
        _Pragma("unroll")                                                          \
        for (int mt = 0; mt < 4; ++mt)                                             \
            _Pragma("unroll")                                                      \
            for (int r = 0; r < 4; ++r) {                                          \
                int tok = mt*16 + l4*4 + r;                                        \
                float u = a1[mt][r] + b1;                                          \
                *(bf16*)((GB) + tok*256 + ((2*cw) ^ ((tok&7)<<4))) = (bf16)gelu_f(u); \
            }                                                                      \
    }

    FC1_CHUNK(0, sm + 16384)
#pragma unroll
    for (int c4 = 0; c4 < 4; ++c4) {
        __syncthreads();                                  // g[c4&1] ready
        if (c4 < 3) {
            char* gb = sm + 16384 + (((c4+1)&1) << 14);
            FC1_CHUNK(c4+1, gb)                           // overlaps fc2 below
        }
        const char* gcur = sm + 16384 + ((c4&1) << 14);
#pragma unroll
        for (int ks = 0; ks < 4; ++ks) {
            bf16x8 bfr = *(const bf16x8*)(wfc2T + cw*512 + c4*128 + ks*32 + l4*8);
#pragma unroll
            for (int mt = 0; mt < 4; ++mt) {
                int tok = mt*16 + l15;
                bf16x8 afr = *(const bf16x8*)(gcur + tok*256 + ((ks*64 + l4*16) ^ ((tok&7)<<4)));
                acc2[mt] = MFMA16(afr, bfr, acc2[mt]);
            }
        }
    }
#undef FC1_CHUNK
    // H and gA last read before the c4=3 barrier -> [0:32K) safe to dump now

    // residual (re-read win2 f32) + dump f32 + BCHW writeback
    {
        float bf_ = b_fc2[cw];
#pragma unroll
        for (int mt = 0; mt < 4; ++mt)
#pragma unroll
            for (int r = 0; r < 4; ++r) {
                int tok = mt*16 + l4*4 + r;
                float res = w2[tok*128 + cw];
                *(float*)(sm + tok*512 + ((cw*4) ^ ((tok&15)<<4))) = res + acc2[mt][r] + bf_;
            }
    }
    __syncthreads();
#pragma unroll
    for (int it = 0; it < 4; ++it) {
        int idx = it*512 + tid;
        int c = idx >> 4, t2 = idx & 15;
        int row = t2 >> 1, col0 = (t2 & 1) * 4;
        f32x4 v;
#pragma unroll
        for (int e = 0; e < 4; ++e) {
            int t = row*8 + col0 + e;
            v[e] = *(const float*)(sm + t*512 + ((c*4) ^ ((t&15)<<4)));
        }
        *(f32x4*)(outw + (size_t)c*65536 + row*256 + col0) = v;
    }
}

// ---------------------------------------------------------------------------
// fallback: R9 monolithic fused kernel (used if ws too small for win2tm)
// ---------------------------------------------------------------------------
__global__ __launch_bounds__(512, 4) void swin_fused(
    const float* __restrict__ x,
    const float* __restrict__ ln1_g, const float* __restrict__ ln1_b,
    const float* __restrict__ b_qkv, const float* __restrict__ b_proj,
    const float* __restrict__ ln2_g, const float* __restrict__ ln2_b,
    const float* __restrict__ b_fc1, const float* __restrict__ b_fc2,
    const bf16* __restrict__ wqkvT, const bf16* __restrict__ wprojT,
    const bf16* __restrict__ wfc1T, const bf16* __restrict__ wfc2T,
    const float* __restrict__ bN,
    float* __restrict__ out)
{
    __shared__ __align__(16) char sm[49152];

    const int tid  = threadIdx.x;
    const int lane = tid & 63;
    const int wv   = tid >> 6;
    const int l15  = lane & 15;
    const int l4   = (lane >> 4) & 3;
    const int l31  = lane & 31;
    const int hi   = lane >> 5;
    const int fmt  = wv >> 1;
    const int fn0  = (wv & 1) * 64;

    const int wid = ((blockIdx.x & 7) << 9) | (blockIdx.x >> 3);
    const int bb  = wid >> 10;
    const int hw  = (wid >> 5) & 31;
    const int wwi = wid & 31;
    const size_t base = (size_t)bb * 8388608 + (size_t)hw * 2048 + (size_t)wwi * 8;
    const float* xw   = x   + base;
    float*       outw = out + base;

#pragma unroll
    for (int it = 0; it < 4; ++it) {
        int idx = it*512 + tid;
        int c = idx >> 4, t2 = idx & 15;
        int row = t2 >> 1, col0 = (t2 & 1) * 4;
        f32x4 v = *(const f32x4*)(xw + (size_t)c*65536 + row*256 + col0);
#pragma unroll
        for (int e = 0; e < 4; ++e) {
            int t = row*8 + col0 + e;
            *(bf16*)(sm + t*256 + ((2*c) ^ ((t&7)<<4))) = (bf16)v[e];
        }
    }
    __syncthreads();

    uint32_t winp[2][4];
#pragma unroll
    for (int r = 0; r < 4; ++r) {
        int tok = fmt*16 + l4*4 + r;
        int swz = (tok & 7) << 4;
        const char* rowp = sm + tok*256;
        uint32_t c0 = *(const uint16_t*)(rowp + ((2*(fn0 +  0 + l15)) ^ swz));
        uint32_t c1 = *(const uint16_t*)(rowp + ((2*(fn0 + 16 + l15)) ^ swz));
        uint32_t c2 = *(const uint16_t*)(rowp + ((2*(fn0 + 32 + l15)) ^ swz));
        uint32_t c3 = *(const uint16_t*)(rowp + ((2*(fn0 + 48 + l15)) ^ swz));
        winp[0][r] = c0 | (c1 << 16);
        winp[1][r] = c2 | (c3 << 16);
    }

    {
        const int t = tid >> 3, p = tid & 7;
        const int swz = (t & 7) << 4;
        float vv[16];
        float s = 0.f, s2 = 0.f;
#pragma unroll
        for (int hlf = 0; hlf < 2; ++hlf) {
            bf16x8 xv = *(const bf16x8*)(sm + t*256 + ((p*32 + hlf*16) ^ swz));
#pragma unroll
            for (int e = 0; e < 8; ++e) { float f = (float)xv[e]; vv[hlf*8+e] = f; s += f; s2 += f*f; }
        }
#pragma unroll
        for (int m = 1; m < 8; m <<= 1) { s += __shfl_xor(s, m, 64); s2 += __shfl_xor(s2, m, 64); }
        const float mean = s * 0.0078125f;
        const float rs = rsqrtf(s2 * 0.0078125f - mean*mean + 1e-5f);
#pragma unroll
        for (int hlf = 0; hlf < 2; ++hlf) {
            bf16x8 hv;
#pragma unroll
            for (int e = 0; e < 8; ++e) {
                int c = p*16 + hlf*8 + e;
                hv[e] = (bf16)((vv[hlf*8+e] - mean) * rs * ln1_g[c] + ln1_b[c]);
            }
            *(bf16x8*)(sm + 16384 + t*256 + ((p*32 + hlf*16) ^ swz)) = hv;
        }
    }
    __syncthreads();

    {
        const float SCALE = 0.35355339059327373f;
        const int nq0 = wv * 32;
        const int nv  = 256 + wv*16 + l15;
        const float bb0 = b_qkv[nq0 + l15];
        const float bb1 = b_qkv[nq0 + 16 + l15];
        const float bbv = b_qkv[nv];
        const bool isq = (nq0 < 128);
        char* rb = isq ? (sm + 16384) : (sm + 32768);
        const float sc = isq ? SCALE : 1.0f;
        const int c0 = (nq0 & 127) + l15;
        const int c1 = ((nq0 + 16) & 127) + l15;
#pragma unroll
        for (int half = 0; half < 2; ++half) {
            f32x4 a0[2], a1[2], avh[2];
#pragma unroll
            for (int m2 = 0; m2 < 2; ++m2) { a0[m2] = zero4(); a1[m2] = zero4(); avh[m2] = zero4(); }
#pragma unroll
            for (int ks = 0; ks < 4; ++ks) {
                bf16x8 bq0 = *(const bf16x8*)(wqkvT + (nq0      + l15)*128 + ks*32 + l4*8);
                bf16x8 bq1 = *(const bf16x8*)(wqkvT + (nq0 + 16 + l15)*128 + ks*32 + l4*8);
                bf16x8 bv  = *(const bf16x8*)(wqkvT + nv*128 + ks*32 + l4*8);
#pragma unroll
                for (int m2 = 0; m2 < 2; ++m2) {
                    int tok = half*32 + m2*16 + l15;
                    bf16x8 afr = *(const bf16x8*)(sm + 16384 + tok*256 + ((ks*64 + l4*16) ^ ((tok&7)<<4)));
                    a0[m2]  = MFMA16(afr, bq0, a0[m2]);
                    a1[m2]  = MFMA16(afr, bq1, a1[m2]);
                    avh[m2] = MFMA16(afr, bv,  avh[m2]);
                }
            }
            __syncthreads();
#pragma unroll
            for (int m2 = 0; m2 < 2; ++m2)
#pragma unroll
                for (int r = 0; r < 4; ++r) {
                    int tok = half*32 + m2*16 + l4*4 + r;
                    int swz = (tok & 7) << 4;
                    *(bf16*)(rb + tok*256 + ((2*c0) ^ swz)) = (bf16)((a0[m2][r] + bb0) * sc);
                    *(bf16*)(rb + tok*256 + ((2*c1) ^ swz)) = (bf16)((a1[m2][r] + bb1) * sc);
                }
            {
                int d = l15;
                char* vb = sm + wv*2048 + d*128;
                int sz = (d & 7) << 4;
#pragma unroll
                for (int m2 = 0; m2 < 2; ++m2) {
                    int t0 = half*32 + m2*16 + l4*4;
                    *(uint32_t*)(vb + ((2*t0)     ^ sz)) = packbf(avh[m2][0]+bbv, avh[m2][1]+bbv);
                    *(uint32_t*)(vb + ((2*t0 + 4) ^ sz)) = packbf(avh[m2][2]+bbv, avh[m2][3]+bbv);
                }
            }
        }
    }
    __syncthreads();

    {
        bf16x8 kf[2];
#pragma unroll
        for (int tk = 0; tk < 2; ++tk) {
            int tok = tk*32 + l31;
            kf[tk] = *(const bf16x8*)(sm + 32768 + tok*256 + ((wv*32 + hi*16) ^ ((tok&7)<<4)));
        }
        __syncthreads();
#pragma unroll
        for (int tq = 0; tq < 2; ++tq) {
            int q = tq*32 + l31;
            bf16x8 qf = *(const bf16x8*)(sm + 16384 + q*256 + ((wv*32 + hi*16) ^ ((q&7)<<4)));
            const float* bq = bN + wv*4096 + q*64 + 4*hi;
            float ss, ri;
            uint32_t own[16];
            {
                f32x16 s0, s1;
#pragma unroll
                for (int g4 = 0; g4 < 4; ++g4) {
                    f32x4 b0 = *(const f32x4*)(bq + g4*8);
                    f32x4 b1 = *(const f32x4*)(bq + 32 + g4*8);
#pragma unroll
                    for (int e = 0; e < 4; ++e) { s0[g4*4+e] = b0[e]; s1[g4*4+e] = b1[e]; }
                }
                s0 = MFMA32(kf[0], qf, s0);
                s1 = MFMA32(kf[1], qf, s1);
                ss = 0.f;
#pragma unroll
                for (int r = 0; r < 16; ++r) {
                    s0[r] = __expf(s0[r]);
                    s1[r] = __expf(s1[r]);
                    ss += s0[r] + s1[r];
                }
#pragma unroll
                for (int ks = 0; ks < 4; ++ks)
#pragma unroll
                    for (int i = 0; i < 4; ++i) {
                        const int j = 2*(i&1) + 4*((2*ks + (i>>1)) & 3) + 16*(ks>>1);
                        if (j < 16) own[ks*4+i] = packbf(s0[j], s0[j+1]);
                        else        own[ks*4+i] = packbf(s1[j-16], s1[j-15]);
                    }
            }
            ss += __shfl_xor(ss, 32, 64);
            ri = 1.0f / ss;
            f32x16 Ot;
#pragma unroll
            for (int i = 0; i < 16; ++i) Ot[i] = 0.f;
#pragma unroll
            for (int ks = 0; ks < 4; ++ks) {
                uint32_t sw0 = __shfl_xor(own[ks*4+0], 32, 64);
                uint32_t sw1 = __shfl_xor(own[ks*4+1], 32, 64);
                uint32_t sw2 = __shfl_xor(own[ks*4+2], 32, 64);
                uint32_t sw3 = __shfl_xor(own[ks*4+3], 32, 64);
                uint32_t w0 = hi ? sw2          : own[ks*4+0];
                uint32_t w1 = hi ? sw3          : own[ks*4+1];
                uint32_t w2 = hi ? own[ks*4+2]  : sw0;
                uint32_t w3 = hi ? own[ks*4+3]  : sw1;
                bf16x8 pf = frag_from_words(w0, w1, w2, w3);
                int dd = l31 & 15;
                bf16x8 vf = *(const bf16x8*)(sm + wv*2048 + dd*128
                                             + ((ks*32 + hi*16) ^ ((dd&7)<<4)));
                Ot = MFMA32(vf, pf, Ot);
            }
#pragma unroll
            for (int r = 0; r < 8; r += 2) {
                int d = (r&3) + 8*(r>>2) + 4*hi;
                *(uint32_t*)(sm + 32768 + q*256 + ((2*(wv*16 + d)) ^ ((q&7)<<4)))
                    = packbf(Ot[r]*ri, Ot[r+1]*ri);
            }
        }
    }
    __syncthreads();

    float win2[4][4];
    {
        f32x4 acc[4];
#pragma unroll
        for (int nt = 0; nt < 4; ++nt) acc[nt] = zero4();
#pragma unroll
        for (int ks = 0; ks < 4; ++ks) {
            int tok = fmt*16 + l15;
            bf16x8 afr = *(const bf16x8*)(sm + 32768 + tok*256 + ((ks*64 + l4*16) ^ ((tok&7)<<4)));
#pragma unroll
            for (int nt = 0; nt < 4; ++nt) {
                int n = fn0 + nt*16 + l15;
                bf16x8 bfr = *(const bf16x8*)(wprojT + n*128 + ks*32 + l4*8);
                acc[nt] = MFMA16(afr, bfr, acc[nt]);
            }
        }
#pragma unroll
        for (int nt = 0; nt < 4; ++nt) {
            float bp = b_proj[fn0 + nt*16 + l15];
#pragma unroll
            for (int r = 0; r < 4; ++r) {
                uint32_t w = winp[nt >> 1][r];
                float xr = uf((nt & 1) ? (w & 0xffff0000u) : (w << 16));
                win2[nt][r] = xr + acc[nt][r] + bp;
            }
        }
    }

    {
        float s[4], s2[4];
#pragma unroll
        for (int r = 0; r < 4; ++r) {
            s[r]  = win2[0][r] + win2[1][r] + win2[2][r] + win2[3][r];
            s2[r] = win2[0][r]*win2[0][r] + win2[1][r]*win2[1][r]
                  + win2[2][r]*win2[2][r] + win2[3][r]*win2[3][r];
#pragma unroll
            for (int m = 1; m < 16; m <<= 1) {
                s[r]  += __shfl_xor(s[r],  m, 64);
                s2[r] += __shfl_xor(s2[r], m, 64);
            }
        }
        float2* scr = (float2*)sm;
        if (l15 == 0) {
#pragma unroll
            for (int r = 0; r < 4; ++r) {
                int tok = fmt*16 + l4*4 + r;
                scr[tok*2 + (wv&1)] = make_float2(s[r], s2[r]);
            }
        }
        __syncthreads();
        float mean[4], rstd[4];
#pragma unroll
        for (int r = 0; r < 4; ++r) {
            int tok = fmt*16 + l4*4 + r;
            float2 p = scr[tok*2 + ((wv&1)^1)];
            float tot = s[r] + p.x, tot2 = s2[r] + p.y;
            float m = tot * 0.0078125f;
            mean[r] = m;
            rstd[r] = rsqrtf(tot2*0.0078125f - m*m + 1e-5f);
        }
#pragma unroll
        for (int nt = 0; nt < 4; ++nt) {
            int c = fn0 + nt*16 + l15;
            float gg = ln2_g[c], bb2 = ln2_b[c];
#pragma unroll
            for (int r = 0; r < 4; ++r) {
                int tok = fmt*16 + l4*4 + r;
                *(bf16*)(sm + 16384 + tok*256 + ((2*c) ^ ((tok&7)<<4)))
                    = (bf16)((win2[nt][r] - mean[r]) * rstd[r] * gg + bb2);
            }
        }
    }
    __syncthreads();

    {
        f32x4 acc2[4];
#pragma unroll
        for (int nt = 0; nt < 4; ++nt) acc2[nt] = zero4();
#pragma unroll
        for (int c4 = 0; c4 < 4; ++c4) {
            char* gbuf = (c4 & 1) ? (sm + 32768) : sm;
            {
                f32x4 a1[4];
#pragma unroll
                for (int nt = 0; nt < 4; ++nt) a1[nt] = zero4();
#pragma unroll
                for (int ks = 0; ks < 4; ++ks) {
                    int tok = fmt*16 + l15;
                    bf16x8 afr = *(const bf16x8*)(sm + 16384 + tok*256 + ((ks*64 + l4*16) ^ ((tok&7)<<4)));
#pragma unroll
                    for (int nt = 0; nt < 4; ++nt) {
                        int n = c4*128 + fn0 + nt*16 + l15;
                        bf16x8 bfr = *(const bf16x8*)(wfc1T + n*128 + ks*32 + l4*8);
                        a1[nt] = MFMA16(afr, bfr, a1[nt]);
                    }
                }
#pragma unroll
                for (int nt = 0; nt < 4; ++nt) {
                    int cl = fn0 + nt*16 + l15;
                    float b1 = b_fc1[c4*128 + cl];
#pragma unroll
                    for (int r = 0; r < 4; ++r) {
                        int tok = fmt*16 + l4*4 + r;
                        float u = a1[nt][r] + b1;
                        *(bf16*)(gbuf + tok*256 + ((2*cl) ^ ((tok&7)<<4))) = (bf16)gelu_f(u);
                    }
                }
            }
            __syncthreads();
#pragma unroll
            for (int ks = 0; ks < 4; ++ks) {
                int tok = fmt*16 + l15;
                bf16x8 afr = *(const bf16x8*)(gbuf + tok*256 + ((ks*64 + l4*16) ^ ((tok&7)<<4)));
#pragma unroll
                for (int nt = 0; nt < 4; ++nt) {
                    int n = fn0 + nt*16 + l15;
                    bf16x8 bfr = *(const bf16x8*)(wfc2T + n*512 + c4*128 + ks*32 + l4*8);
                    acc2[nt] = MFMA16(afr, bfr, acc2[nt]);
                }
            }
        }
#pragma unroll
        for (int nt = 0; nt < 4; ++nt) {
            float bf_ = b_fc2[fn0 + nt*16 + l15];
#pragma unroll
            for (int r = 0; r < 4; ++r) win2[nt][r] += acc2[nt][r] + bf_;
        }
    }
    __syncthreads();

#pragma unroll
    for (int nt = 0; nt < 4; ++nt)
#pragma unroll
        for (int r = 0; r < 4; ++r) {
            int tok = fmt*16 + l4*4 + r;
            int c   = fn0 + nt*16 + l15;
            *(float*)(sm + tok*512 + ((c*4) ^ ((tok&15)<<4))) = win2[nt][r];
        }
    __syncthreads();
#pragma unroll
    for (int it = 0; it < 4; ++it) {
        int idx = it*512 + tid;
        int c = idx >> 4, t2 = idx & 15;
        int row = t2 >> 1, col0 = (t2 & 1) * 4;
        f32x4 v;
#pragma unroll
        for (int e = 0; e < 4; ++e) {
            int t = row*8 + col0 + e;
            v[e] = *(const float*)(sm + t*512 + ((c*4) ^ ((t&15)<<4)));
        }
        *(f32x4*)(outw + (size_t)c*65536 + row*256 + col0) = v;
    }
}

extern "C" void kernel_launch(void* const* d_in, const int* in_sizes, int n_in,
                              void* d_out, int out_size, void* d_ws, size_t ws_size,
                              hipStream_t stream) {
    const float* x      = (const float*)d_in[0];
    const float* ln1_g  = (const float*)d_in[1];
    const float* ln1_b  = (const float*)d_in[2];
    const float* w_qkv  = (const float*)d_in[3];
    const float* b_qkv  = (const float*)d_in[4];
    const float* w_proj = (const float*)d_in[5];
    const float* b_proj = (const float*)d_in[6];
    const float* btab   = (const float*)d_in[7];
    const float* ln2_g  = (const float*)d_in[8];
    const float* ln2_b  = (const float*)d_in[9];
    const float* w_fc1  = (const float*)d_in[10];
    const float* b_fc1  = (const float*)d_in[11];
    const float* w_fc2  = (const float*)d_in[12];
    const float* b_fc2  = (const float*)d_in[13];
    const int*   relix  = (const int*)d_in[14];
    float* out = (float*)d_out;

    char* ws = (char*)d_ws;
    bf16*  wqkvT  = (bf16*)(ws);
    bf16*  wprojT = (bf16*)(ws + 98304);
    bf16*  wfc1T  = (bf16*)(ws + 131072);
    bf16*  wfc2T  = (bf16*)(ws + 262144);
    float* bN     = (float*)(ws + 393216);
    float* win2tm = (float*)(ws + 524288);

    prep_kernel<<<dim3(448), dim3(512), 0, stream>>>(
        w_qkv, w_proj, w_fc1, w_fc2, btab, relix,
        wqkvT, wprojT, wfc1T, wfc2T, bN);

    const size_t need = 524288ull + 134217728ull;
    if (ws_size >= need) {
        swin_attn<<<dim3(4096), dim3(512), 0, stream>>>(
            x, ln1_g, ln1_b, b_qkv, b_proj, wqkvT, wprojT, bN, win2tm);
        swin_mlp<<<dim3(4096), dim3(512), 0, stream>>>(
            win2tm, ln2_g, ln2_b, b_fc1, b_fc2, wfc1T, wfc2T, out);
    } else {
        swin_fused<<<dim3(4096), dim3(512), 0, stream>>>(
            x, ln1_g, ln1_b, b_qkv, b_proj, ln2_g, ln2_b, b_fc1, b_fc2,
            wqkvT, wprojT, wfc1T, wfc2T, bN, out);
    }
}

// Round 13
// 426.892 us; speedup vs baseline: 1.8481x; 1.0870x over previous
//
#include <hip/hip_runtime.h>
#include <hip/hip_bf16.h>
#include <stdint.h>

typedef __bf16 bf16;
typedef __bf16 bf16x8 __attribute__((ext_vector_type(8)));
typedef float  f32x4  __attribute__((ext_vector_type(4)));
typedef float  f32x16 __attribute__((ext_vector_type(16)));

#define MFMA16(a,b,c) __builtin_amdgcn_mfma_f32_16x16x32_bf16(a,b,c,0,0,0)
#define MFMA32(a,b,c) __builtin_amdgcn_mfma_f32_32x32x16_bf16(a,b,c,0,0,0)

__device__ __forceinline__ f32x4 zero4() { f32x4 z; z[0]=0.f; z[1]=0.f; z[2]=0.f; z[3]=0.f; return z; }

__device__ __forceinline__ uint32_t packbf(float lo, float hi) {
    union { bf16 b[2]; uint32_t u; } t;
    t.b[0] = (bf16)lo; t.b[1] = (bf16)hi;
    return t.u;
}
__device__ __forceinline__ bf16x8 frag_from_words(uint32_t w0, uint32_t w1, uint32_t w2, uint32_t w3) {
    union { uint32_t u[4]; bf16x8 v; } t;
    t.u[0] = w0; t.u[1] = w1; t.u[2] = w2; t.u[3] = w3;
    return t.v;
}
__device__ __forceinline__ float uf(uint32_t u) {
    union { uint32_t u; float f; } t; t.u = u; return t.f;
}
// fast GELU (tanh form, max err ~3e-3)
__device__ __forceinline__ float gelu_f(float u) {
    float u2 = u * u;
    float y  = u * (0.7978845608f + 0.0356774081f * u2);
    float e  = __expf(2.0f * y);
    float t  = 1.0f - 2.0f / (e + 1.0f);
    return 0.5f * u * (1.0f + t);
}

// ---------------------------------------------------------------------------
// prep: weights f32 -> bf16 [n][k]; bias matrix natural: bN[h][q][k]
// ws layout (bytes):
//   0      : wqkvT  [384][128] bf16   (98304)
//   98304  : wprojT [128][128] bf16   (32768)
//   131072 : wfc1T  [512][128] bf16   (131072)
//   262144 : wfc2T  [128][512] bf16   (131072)
//   393216 : bN     [8][64][64] f32   (131072)
//   524288 : win2tm [4096][64][128] f32 (134217728)   [split path only]
// ---------------------------------------------------------------------------
__global__ __launch_bounds__(512) void prep_kernel(
    const float* __restrict__ wqkv, const float* __restrict__ wproj,
    const float* __restrict__ wfc1, const float* __restrict__ wfc2,
    const float* __restrict__ btab, const int* __restrict__ relidx,
    bf16* __restrict__ wqkvT, bf16* __restrict__ wprojT,
    bf16* __restrict__ wfc1T, bf16* __restrict__ wfc2T,
    float* __restrict__ bN)
{
    int i = blockIdx.x * 512 + threadIdx.x;
    if (i < 49152) { int n = i >> 7, k = i & 127; wqkvT[i] = (bf16)wqkv[k*384 + n]; return; }
    i -= 49152;
    if (i < 16384) { int n = i >> 7, k = i & 127; wprojT[i] = (bf16)wproj[k*128 + n]; return; }
    i -= 16384;
    if (i < 65536) { int n = i >> 7, k = i & 127; wfc1T[i] = (bf16)wfc1[k*512 + n]; return; }
    i -= 65536;
    if (i < 65536) { int n = i >> 9, k = i & 511; wfc2T[i] = (bf16)wfc2[k*128 + n]; return; }
    i -= 65536;
    if (i < 32768) { int h = i >> 12, q = (i >> 6) & 63, k = i & 63;
                     bN[i] = btab[relidx[q*64 + k]*8 + h]; }
}

// ---------------------------------------------------------------------------
// kernel1: x -> LN1 -> QKV -> attention -> proj + residual -> win2 (token-major f32)
// R13: sequential k-halves in P4 (s 16 AGPR not 32), o stored into B (own-col
// slices, race-free under row-uniform swizzle; B4 barrier deleted), col-sliced
// proj. Target: total regs <= ~85 -> 3 blocks/CU.
// LDS 49152: A x->vT | B h->q->o | C k (intact through P4).
// ---------------------------------------------------------------------------
__global__ __launch_bounds__(512, 4) void swin_attn(
    const float* __restrict__ x,
    const float* __restrict__ ln1_g, const float* __restrict__ ln1_b,
    const float* __restrict__ b_qkv, const float* __restrict__ b_proj,
    const bf16* __restrict__ wqkvT, const bf16* __restrict__ wprojT,
    const float* __restrict__ bN,
    float* __restrict__ win2tm)
{
    __shared__ __align__(16) char sm[49152];

    const int tid  = threadIdx.x;
    const int lane = tid & 63;
    const int wv   = tid >> 6;
    const int l15  = lane & 15;
    const int l4   = (lane >> 4) & 3;
    const int l31  = lane & 31;
    const int hi   = lane >> 5;
    const int cw   = wv*16 + l15;          // proj output column

    const int wid = ((blockIdx.x & 7) << 9) | (blockIdx.x >> 3);
    const int bb  = wid >> 10;
    const int hw  = (wid >> 5) & 31;
    const int wwi = wid & 31;
    const size_t base = (size_t)bb * 8388608 + (size_t)hw * 2048 + (size_t)wwi * 8;
    const float* xw = x + base;

    // P1: stage x window as bf16 [tok][c] into A
#pragma unroll
    for (int it = 0; it < 4; ++it) {
        int idx = it*512 + tid;
        int c = idx >> 4, t2 = idx & 15;
        int row = t2 >> 1, col0 = (t2 & 1) * 4;
        f32x4 v = *(const f32x4*)(xw + (size_t)c*65536 + row*256 + col0);
#pragma unroll
        for (int e = 0; e < 4; ++e) {
            int t = row*8 + col0 + e;
            *(bf16*)(sm + t*256 + ((2*c) ^ ((t&7)<<4))) = (bf16)v[e];
        }
    }
    __syncthreads();   // B1

    // P1.5: residual -> 8 packed-bf16 regs (col-sliced proj layout: col cw)
    uint32_t winp[4][2];
#pragma unroll
    for (int mt = 0; mt < 4; ++mt)
#pragma unroll
        for (int rp = 0; rp < 2; ++rp) {
            int tok0 = mt*16 + l4*4 + 2*rp;
            int tok1 = tok0 + 1;
            uint32_t u0 = *(const uint16_t*)(sm + tok0*256 + ((2*cw) ^ ((tok0&7)<<4)));
            uint32_t u1 = *(const uint16_t*)(sm + tok1*256 + ((2*cw) ^ ((tok1&7)<<4)));
            winp[mt][rp] = u0 | (u1 << 16);
        }

    // P2: LN1 (reads A) -> h in B
    {
        const int t = tid >> 3, p = tid & 7;
        const int swz = (t & 7) << 4;
        float vv[16];
        float s = 0.f, s2 = 0.f;
#pragma unroll
        for (int hlf = 0; hlf < 2; ++hlf) {
            bf16x8 xv = *(const bf16x8*)(sm + t*256 + ((p*32 + hlf*16) ^ swz));
#pragma unroll
            for (int e = 0; e < 8; ++e) { float f = (float)xv[e]; vv[hlf*8+e] = f; s += f; s2 += f*f; }
        }
#pragma unroll
        for (int m = 1; m < 8; m <<= 1) { s += __shfl_xor(s, m, 64); s2 += __shfl_xor(s2, m, 64); }
        const float mean = s * 0.0078125f;
        const float rs = rsqrtf(s2 * 0.0078125f - mean*mean + 1e-5f);
#pragma unroll
        for (int hlf = 0; hlf < 2; ++hlf) {
            bf16x8 hv;
#pragma unroll
            for (int e = 0; e < 8; ++e) {
                int c = p*16 + hlf*8 + e;
                hv[e] = (bf16)((vv[hlf*8+e] - mean) * rs * ln1_g[c] + ln1_b[c]);
            }
            *(bf16x8*)(sm + 16384 + t*256 + ((p*32 + hlf*16) ^ swz)) = hv;
        }
    }
    __syncthreads();   // B2 — A free for vT

    // P3: QKV GEMM, two mt-half-passes (q->B, k->C, vT->A)
    {
        const float SCALE = 0.35355339059327373f;
        const int nq0 = wv * 32;
        const int nv  = 256 + wv*16 + l15;
        const float bb0 = b_qkv[nq0 + l15];
        const float bb1 = b_qkv[nq0 + 16 + l15];
        const float bbv = b_qkv[nv];
        const bool isq = (nq0 < 128);
        char* rb = isq ? (sm + 16384) : (sm + 32768);
        const float sc = isq ? SCALE : 1.0f;
        const int c0 = (nq0 & 127) + l15;
        const int c1 = ((nq0 + 16) & 127) + l15;
#pragma unroll
        for (int half = 0; half < 2; ++half) {
            f32x4 a0[2], a1[2], avh[2];
#pragma unroll
            for (int m2 = 0; m2 < 2; ++m2) { a0[m2] = zero4(); a1[m2] = zero4(); avh[m2] = zero4(); }
#pragma unroll
            for (int ks = 0; ks < 4; ++ks) {
                bf16x8 bq0 = *(const bf16x8*)(wqkvT + (nq0      + l15)*128 + ks*32 + l4*8);
                bf16x8 bq1 = *(const bf16x8*)(wqkvT + (nq0 + 16 + l15)*128 + ks*32 + l4*8);
                bf16x8 bv  = *(const bf16x8*)(wqkvT + nv*128 + ks*32 + l4*8);
#pragma unroll
                for (int m2 = 0; m2 < 2; ++m2) {
                    int tok = half*32 + m2*16 + l15;
                    bf16x8 afr = *(const bf16x8*)(sm + 16384 + tok*256 + ((ks*64 + l4*16) ^ ((tok&7)<<4)));
                    a0[m2]  = MFMA16(afr, bq0, a0[m2]);
                    a1[m2]  = MFMA16(afr, bq1, a1[m2]);
                    avh[m2] = MFMA16(afr, bv,  avh[m2]);
                }
            }
            __syncthreads();   // B3a / B3b
#pragma unroll
            for (int m2 = 0; m2 < 2; ++m2)
#pragma unroll
                for (int r = 0; r < 4; ++r) {
                    int tok = half*32 + m2*16 + l4*4 + r;
                    int swz = (tok & 7) << 4;
                    *(bf16*)(rb + tok*256 + ((2*c0) ^ swz)) = (bf16)((a0[m2][r] + bb0) * sc);
                    *(bf16*)(rb + tok*256 + ((2*c1) ^ swz)) = (bf16)((a1[m2][r] + bb1) * sc);
                }
            {
                int d = l15;
                char* vb = sm + wv*2048 + d*128;
                int sz = (d & 7) << 4;
#pragma unroll
                for (int m2 = 0; m2 < 2; ++m2) {
                    int t0 = half*32 + m2*16 + l4*4;
                    *(uint32_t*)(vb + ((2*t0)     ^ sz)) = packbf(avh[m2][0]+bbv, avh[m2][1]+bbv);
                    *(uint32_t*)(vb + ((2*t0 + 4) ^ sz)) = packbf(avh[m2][2]+bbv, avh[m2][3]+bbv);
                }
            }
        }
    }
    __syncthreads();   // B3

    // P4: attention (wave = head), sequential k-halves, bias as MFMA C-in,
    //     late normalize; o -> B (own-column slice, race-free)
    {
#pragma unroll
        for (int tq = 0; tq < 2; ++tq) {
            int q = tq*32 + l31;
            bf16x8 qf = *(const bf16x8*)(sm + 16384 + q*256 + ((wv*32 + hi*16) ^ ((q&7)<<4)));
            f32x16 Ot;
#pragma unroll
            for (int i = 0; i < 16; ++i) Ot[i] = 0.f;
            float ss = 0.f;
#pragma unroll
            for (int kh = 0; kh < 2; ++kh) {
                int kt = kh*32 + l31;
                bf16x8 kfh = *(const bf16x8*)(sm + 32768 + kt*256 + ((wv*32 + hi*16) ^ ((kt&7)<<4)));
                const float* bq = bN + wv*4096 + q*64 + kh*32 + 4*hi;
                f32x16 s;
#pragma unroll
                for (int g4 = 0; g4 < 4; ++g4) {
                    f32x4 b0 = *(const f32x4*)(bq + g4*8);
#pragma unroll
                    for (int e = 0; e < 4; ++e) s[g4*4+e] = b0[e];
                }
                s = MFMA32(kfh, qf, s);
#pragma unroll
                for (int r = 0; r < 16; ++r) { s[r] = __expf(s[r]); ss += s[r]; }
                uint32_t ow[8];
#pragma unroll
                for (int ksl = 0; ksl < 2; ++ksl)
#pragma unroll
                    for (int i = 0; i < 4; ++i) {
                        const int j = 2*(i&1) + 4*((2*ksl + (i>>1)) & 3);
                        ow[ksl*4+i] = packbf(s[j], s[j+1]);
                    }
#pragma unroll
                for (int ksl = 0; ksl < 2; ++ksl) {
                    uint32_t sw0 = __shfl_xor(ow[ksl*4+0], 32, 64);
                    uint32_t sw1 = __shfl_xor(ow[ksl*4+1], 32, 64);
                    uint32_t sw2 = __shfl_xor(ow[ksl*4+2], 32, 64);
                    uint32_t sw3 = __shfl_xor(ow[ksl*4+3], 32, 64);
                    uint32_t w0  = hi ? sw2           : ow[ksl*4+0];
                    uint32_t w1  = hi ? sw3           : ow[ksl*4+1];
                    uint32_t w2_ = hi ? ow[ksl*4+2]   : sw0;
                    uint32_t w3  = hi ? ow[ksl*4+3]   : sw1;
                    bf16x8 pf = frag_from_words(w0, w1, w2_, w3);
                    int dd = l31 & 15;
                    int ks = 2*kh + ksl;
                    bf16x8 vf = *(const bf16x8*)(sm + wv*2048 + dd*128
                                                 + ((ks*32 + hi*16) ^ ((dd&7)<<4)));
                    Ot = MFMA32(vf, pf, Ot);
                }
            }
            ss += __shfl_xor(ss, 32, 64);
            float ri = 1.0f / ss;
            // o rows for this tq -> B (own-column byte slice under row-uniform swizzle)
#pragma unroll
            for (int r = 0; r < 8; r += 2) {
                int d = (r&3) + 8*(r>>2) + 4*hi;
                *(uint32_t*)(sm + 16384 + q*256 + ((2*(wv*16 + d)) ^ ((q&7)<<4)))
                    = packbf(Ot[r]*ri, Ot[r+1]*ri);
            }
        }
    }
    __syncthreads();   // B5 — all o written before proj reads all columns

    // P5: proj (column-sliced) + residual -> win2 token-major
    {
        f32x4 acc[4];
#pragma unroll
        for (int mt = 0; mt < 4; ++mt) acc[mt] = zero4();
#pragma unroll
        for (int ks = 0; ks < 4; ++ks) {
            bf16x8 bfr = *(const bf16x8*)(wprojT + cw*128 + ks*32 + l4*8);
#pragma unroll
            for (int mt = 0; mt < 4; ++mt) {
                int tok = mt*16 + l15;
                bf16x8 afr = *(const bf16x8*)(sm + 16384 + tok*256 + ((ks*64 + l4*16) ^ ((tok&7)<<4)));
                acc[mt] = MFMA16(afr, bfr, acc[mt]);
            }
        }
        float* w2 = win2tm + (size_t)wid*8192;
        float bp = b_proj[cw];
#pragma unroll
        for (int mt = 0; mt < 4; ++mt)
#pragma unroll
            for (int r = 0; r < 4; ++r) {
                int tok = mt*16 + l4*4 + r;
                uint32_t w = winp[mt][r>>1];
                float xr = uf((r&1) ? (w & 0xffff0000u) : (w << 16));
                w2[tok*128 + cw] = xr + acc[mt][r] + bp;
            }
    }
}

// ---------------------------------------------------------------------------
// kernel2 (column-sliced MLP) — identical to R12
// ---------------------------------------------------------------------------
__global__ __launch_bounds__(512, 4) void swin_mlp(
    const float* __restrict__ win2tm,
    const float* __restrict__ ln2_g, const float* __restrict__ ln2_b,
    const float* __restrict__ b_fc1, const float* __restrict__ b_fc2,
    const bf16* __restrict__ wfc1T, const bf16* __restrict__ wfc2T,
    float* __restrict__ out)
{
    __shared__ __align__(16) char sm[49152];

    const int tid  = threadIdx.x;
    const int lane = tid & 63;
    const int wv   = tid >> 6;
    const int l15  = lane & 15;
    const int l4   = (lane >> 4) & 3;
    const int cw   = wv * 16 + l15;

    const int wid = ((blockIdx.x & 7) << 9) | (blockIdx.x >> 3);
    const int bb  = wid >> 10;
    const int hw  = (wid >> 5) & 31;
    const int wwi = wid & 31;
    const size_t obase = (size_t)bb * 8388608 + (size_t)hw * 2048 + (size_t)wwi * 8;
    float* outw = out + obase;
    const float* w2 = win2tm + (size_t)wid*8192;

    // LN2 straight from global into H (bf16, swizzled)
    {
        const int t = tid >> 3, p = tid & 7;
        const int swz = (t & 7) << 4;
        float vv[16];
        float s = 0.f, s2 = 0.f;
#pragma unroll
        for (int i4 = 0; i4 < 4; ++i4) {
            f32x4 v = *(const f32x4*)(w2 + t*128 + p*16 + i4*4);
#pragma unroll
            for (int e = 0; e < 4; ++e) { float f = v[e]; vv[i4*4+e] = f; s += f; s2 += f*f; }
        }
#pragma unroll
        for (int m = 1; m < 8; m <<= 1) { s += __shfl_xor(s, m, 64); s2 += __shfl_xor(s2, m, 64); }
        const float mean = s * 0.0078125f;
        const float rs = rsqrtf(s2 * 0.0078125f - mean*mean + 1e-5f);
#pragma unroll
        for (int hlf = 0; hlf < 2; ++hlf) {
            bf16x8 hv;
#pragma unroll
            for (int e = 0; e < 8; ++e) {
                int c = p*16 + hlf*8 + e;
                hv[e] = (bf16)((vv[hlf*8+e] - mean) * rs * ln2_g[c] + ln2_b[c]);
            }
            *(bf16x8*)(sm + t*256 + ((p*32 + hlf*16) ^ swz)) = hv;
        }
    }
    __syncthreads();

    f32x4 acc2[4];
#pragma unroll
    for (int mt = 0; mt < 4; ++mt) acc2[mt] = zero4();

#define FC1_CHUNK(C4, GB)                                                          \
    {                                                                              \
        f32x4 a1[4];                                                               \
        a1[0] = zero4(); a1[1] = zero4(); a1[2] = zero4(); a1[3] = zero4();        \
        _Pragma("unroll")                                                          \
        for (int ks = 0; ks < 4; ++ks) {                                           \
            bf16x8 bfr = *(const bf16x8*)(wfc1T + ((C4)*128 + cw)*128 + ks*32 + l4*8); \
            _Pragma("unroll")                                                      \
            for (int mt = 0; mt < 4; ++mt) {                                       \
                int tok = mt*16 + l15;                                             \
                bf16x8 afr = *(const bf16x8*)(sm + tok*256 + ((ks*64 + l4*16) ^ ((tok&7)<<4))); \
                a1[mt] = MFMA16(afr, bfr, a1[mt]);                                 \
            }                                                                      \
        }                                                                          \
        float b1 = b_fc1[(C4)*128 + cw];                                           \
        _Pragma("unroll")                                                          \
        for (int mt = 0; mt < 4; ++mt)                                             \
            _Pragma("unroll")                                                      \
            for (int r = 0; r < 4; ++r) {                                          \
                int tok = mt*16 + l4*4 + r;                                        \
                float u = a1[mt][r] + b1;                                          \
                *(bf16*)((GB) + tok*256 + ((2*cw) ^ ((tok&7)<<4))) = (bf16)gelu_f(u); \
            }                                                                      \
    }

    FC1_CHUNK(0, sm + 16384)
#pragma unroll
    for (int c4 = 0; c4 < 4; ++c4) {
        __syncthreads();
        if (c4 < 3) {
            char* gb = sm + 16384 + (((c4+1)&1) << 14);
            FC1_CHUNK(c4+1, gb)
        }
        const char* gcur = sm + 16384 + ((c4&1) << 14);
#pragma unroll
        for (int ks = 0; ks < 4; ++ks) {
            bf16x8 bfr = *(const bf16x8*)(wfc2T + cw*512 + c4*128 + ks*32 + l4*8);
#pragma unroll
            for (int mt = 0; mt < 4; ++mt) {
                int tok = mt*16 + l15;
                bf16x8 afr = *(const bf16x8*)(gcur + tok*256 + ((ks*64 + l4*16) ^ ((tok&7)<<4)));
                acc2[mt] = MFMA16(afr, bfr, acc2[mt]);
            }
        }
    }
#undef FC1_CHUNK

    {
        float bf_ = b_fc2[cw];
#pragma unroll
        for (int mt = 0; mt < 4; ++mt)
#pragma unroll
            for (int r = 0; r < 4; ++r) {
                int tok = mt*16 + l4*4 + r;
                float res = w2[tok*128 + cw];
                *(float*)(sm + tok*512 + ((cw*4) ^ ((tok&15)<<4))) = res + acc2[mt][r] + bf_;
            }
    }
    __syncthreads();
#pragma unroll
    for (int it = 0; it < 4; ++it) {
        int idx = it*512 + tid;
        int c = idx >> 4, t2 = idx & 15;
        int row = t2 >> 1, col0 = (t2 & 1) * 4;
        f32x4 v;
#pragma unroll
        for (int e = 0; e < 4; ++e) {
            int t = row*8 + col0 + e;
            v[e] = *(const float*)(sm + t*512 + ((c*4) ^ ((t&15)<<4)));
        }
        *(f32x4*)(outw + (size_t)c*65536 + row*256 + col0) = v;
    }
}

// ---------------------------------------------------------------------------
// fallback: R9 monolithic fused kernel (used if ws too small for win2tm)
// ---------------------------------------------------------------------------
__global__ __launch_bounds__(512, 4) void swin_fused(
    const float* __restrict__ x,
    const float* __restrict__ ln1_g, const float* __restrict__ ln1_b,
    const float* __restrict__ b_qkv, const float* __restrict__ b_proj,
    const float* __restrict__ ln2_g, const float* __restrict__ ln2_b,
    const float* __restrict__ b_fc1, const float* __restrict__ b_fc2,
    const bf16* __restrict__ wqkvT, const bf16* __restrict__ wprojT,
    const bf16* __restrict__ wfc1T, const bf16* __restrict__ wfc2T,
    const float* __restrict__ bN,
    float* __restrict__ out)
{
    __shared__ __align__(16) char sm[49152];

    const int tid  = threadIdx.x;
    const int lane = tid & 63;
    const int wv   = tid >> 6;
    const int l15  = lane & 15;
    const int l4   = (lane >> 4) & 3;
    const int l31  = lane & 31;
    const int hi   = lane >> 5;
    const int fmt  = wv >> 1;
    const int fn0  = (wv & 1) * 64;

    const int wid = ((blockIdx.x & 7) << 9) | (blockIdx.x >> 3);
    const int bb  = wid >> 10;
    const int hw  = (wid >> 5) & 31;
    const int wwi = wid & 31;
    const size_t base = (size_t)bb * 8388608 + (size_t)hw * 2048 + (size_t)wwi * 8;
    const float* xw   = x   + base;
    float*       outw = out + base;

#pragma unroll
    for (int it = 0; it < 4; ++it) {
        int idx = it*512 + tid;
        int c = idx >> 4, t2 = idx & 15;
        int row = t2 >> 1, col0 = (t2 & 1) * 4;
        f32x4 v = *(const f32x4*)(xw + (size_t)c*65536 + row*256 + col0);
#pragma unroll
        for (int e = 0; e < 4; ++e) {
            int t = row*8 + col0 + e;
            *(bf16*)(sm + t*256 + ((2*c) ^ ((t&7)<<4))) = (bf16)v[e];
        }
    }
    __syncthreads();

    uint32_t winp[2][4];
#pragma unroll
    for (int r = 0; r < 4; ++r) {
        int tok = fmt*16 + l4*4 + r;
        int swz = (tok & 7) << 4;
        const char* rowp = sm + tok*256;
        uint32_t c0 = *(const uint16_t*)(rowp + ((2*(fn0 +  0 + l15)) ^ swz));
        uint32_t c1 = *(const uint16_t*)(rowp + ((2*(fn0 + 16 + l15)) ^ swz));
        uint32_t c2 = *(const uint16_t*)(rowp + ((2*(fn0 + 32 + l15)) ^ swz));
        uint32_t c3 = *(const uint16_t*)(rowp + ((2*(fn0 + 48 + l15)) ^ swz));
        winp[0][r] = c0 | (c1 << 16);
        winp[1][r] = c2 | (c3 << 16);
    }

    {
        const int t = tid >> 3, p = tid & 7;
        const int swz = (t & 7) << 4;
        float vv[16];
        float s = 0.f, s2 = 0.f;
#pragma unroll
        for (int hlf = 0; hlf < 2; ++hlf) {
            bf16x8 xv = *(const bf16x8*)(sm + t*256 + ((p*32 + hlf*16) ^ swz));
#pragma unroll
            for (int e = 0; e < 8; ++e) { float f = (float)xv[e]; vv[hlf*8+e] = f; s += f; s2 += f*f; }
        }
#pragma unroll
        for (int m = 1; m < 8; m <<= 1) { s += __shfl_xor(s, m, 64); s2 += __shfl_xor(s2, m, 64); }
        const float mean = s * 0.0078125f;
        const float rs = rsqrtf(s2 * 0.0078125f - mean*mean + 1e-5f);
#pragma unroll
        for (int hlf = 0; hlf < 2; ++hlf) {
            bf16x8 hv;
#pragma unroll
            for (int e = 0; e < 8; ++e) {
                int c = p*16 + hlf*8 + e;
                hv[e] = (bf16)((vv[hlf*8+e] - mean) * rs * ln1_g[c] + ln1_b[c]);
            }
            *(bf16x8*)(sm + 16384 + t*256 + ((p*32 + hlf*16) ^ swz)) = hv;
        }
    }
    __syncthreads();

    {
        const float SCALE = 0.35355339059327373f;
        const int nq0 = wv * 32;
        const int nv  = 256 + wv*16 + l15;
        const float bb0 = b_qkv[nq0 + l15];
        const float bb1 = b_qkv[nq0 + 16 + l15];
        const float bbv = b_qkv[nv];
        const bool isq = (nq0 < 128);
        char* rb = isq ? (sm + 16384) : (sm + 32768);
        const float sc = isq ? SCALE : 1.0f;
        const int c0 = (nq0 & 127) + l15;
        const int c1 = ((nq0 + 16) & 127) + l15;
#pragma unroll
        for (int half = 0; half < 2; ++half) {
            f32x4 a0[2], a1[2], avh[2];
#pragma unroll
            for (int m2 = 0; m2 < 2; ++m2) { a0[m2] = zero4(); a1[m2] = zero4(); avh[m2] = zero4(); }
#pragma unroll
            for (int ks = 0; ks < 4; ++ks) {
                bf16x8 bq0 = *(const bf16x8*)(wqkvT + (nq0      + l15)*128 + ks*32 + l4*8);
                bf16x8 bq1 = *(const bf16x8*)(wqkvT + (nq0 + 16 + l15)*128 + ks*32 + l4*8);
                bf16x8 bv  = *(const bf16x8*)(wqkvT + nv*128 + ks*32 + l4*8);
#pragma unroll
                for (int m2 = 0; m2 < 2; ++m2) {
                    int tok = half*32 + m2*16 + l15;
                    bf16x8 afr = *(const bf16x8*)(sm + 16384 + tok*256 + ((ks*64 + l4*16) ^ ((tok&7)<<4)));
                    a0[m2]  = MFMA16(afr, bq0, a0[m2]);
                    a1[m2]  = MFMA16(afr, bq1, a1[m2]);
                    avh[m2] = MFMA16(afr, bv,  avh[m2]);
                }
            }
            __syncthreads();
#pragma unroll
            for (int m2 = 0; m2 < 2; ++m2)
#pragma unroll
                for (int r = 0; r < 4; ++r) {
                    int tok = half*32 + m2*16 + l4*4 + r;
                    int swz = (tok & 7) << 4;
                    *(bf16*)(rb + tok*256 + ((2*c0) ^ swz)) = (bf16)((a0[m2][r] + bb0) * sc);
                    *(bf16*)(rb + tok*256 + ((2*c1) ^ swz)) = (bf16)((a1[m2][r] + bb1) * sc);
                }
            {
                int d = l15;
                char* vb = sm + wv*2048 + d*128;
                int sz = (d & 7) << 4;
#pragma unroll
                for (int m2 = 0; m2 < 2; ++m2) {
                    int t0 = half*32 + m2*16 + l4*4;
                    *(uint32_t*)(vb + ((2*t0)     ^ sz)) = packbf(avh[m2][0]+bbv, avh[m2][1]+bbv);
                    *(uint32_t*)(vb + ((2*t0 + 4) ^ sz)) = packbf(avh[m2][2]+bbv, avh[m2][3]+bbv);
                }
            }
        }
    }
    __syncthreads();

    {
        bf16x8 kf[2];
#pragma unroll
        for (int tk = 0; tk < 2; ++tk) {
            int tok = tk*32 + l31;
            kf[tk] = *(const bf16x8*)(sm + 32768 + tok*256 + ((wv*32 + hi*16) ^ ((tok&7)<<4)));
        }
        __syncthreads();
#pragma unroll
        for (int tq = 0; tq < 2; ++tq) {
            int q = tq*32 + l31;
            bf16x8 qf = *(const bf16x8*)(sm + 16384 + q*256 + ((wv*32 + hi*16) ^ ((q&7)<<4)));
            const float* bq = bN + wv*4096 + q*64 + 4*hi;
            float ss, ri;
            uint32_t own[16];
            {
                f32x16 s0, s1;
#pragma unroll
                for (int g4 = 0; g4 < 4; ++g4) {
                    f32x4 b0 = *(const f32x4*)(bq + g4*8);
                    f32x4 b1 = *(const f32x4*)(bq + 32 + g4*8);
#pragma unroll
                    for (int e = 0; e < 4; ++e) { s0[g4*4+e] = b0[e]; s1[g4*4+e] = b1[e]; }
                }
                s0 = MFMA32(kf[0], qf, s0);
                s1 = MFMA32(kf[1], qf, s1);
                ss = 0.f;
#pragma unroll
                for (int r = 0; r < 16; ++r) {
                    s0[r] = __expf(s0[r]);
                    s1[r] = __expf(s1[r]);
                    ss += s0[r] + s1[r];
                }
#pragma unroll
                for (int ks = 0; ks < 4; ++ks)
#pragma unroll
                    for (int i = 0; i < 4; ++i) {
                        const int j = 2*(i&1) + 4*((2*ks + (i>>1)) & 3) + 16*(ks>>1);
                        if (j < 16) own[ks*4+i] = packbf(s0[j], s0[j+1]);
                        else        own[ks*4+i] = packbf(s1[j-16], s1[j-15]);
                    }
            }
            ss += __shfl_xor(ss, 32, 64);
            ri = 1.0f / ss;
            f32x16 Ot;
#pragma unroll
            for (int i = 0; i < 16; ++i) Ot[i] = 0.f;
#pragma unroll
            for (int ks = 0; ks < 4; ++ks) {
                uint32_t sw0 = __shfl_xor(own[ks*4+0], 32, 64);
                uint32_t sw1 = __shfl_xor(own[ks*4+1], 32, 64);
                uint32_t sw2 = __shfl_xor(own[ks*4+2], 32, 64);
                uint32_t sw3 = __shfl_xor(own[ks*4+3], 32, 64);
                uint32_t w0 = hi ? sw2          : own[ks*4+0];
                uint32_t w1 = hi ? sw3          : own[ks*4+1];
                uint32_t w2 = hi ? own[ks*4+2]  : sw0;
                uint32_t w3 = hi ? own[ks*4+3]  : sw1;
                bf16x8 pf = frag_from_words(w0, w1, w2, w3);
                int dd = l31 & 15;
                bf16x8 vf = *(const bf16x8*)(sm + wv*2048 + dd*128
                                             + ((ks*32 + hi*16) ^ ((dd&7)<<4)));
                Ot = MFMA32(vf, pf, Ot);
            }
#pragma unroll
            for (int r = 0; r < 8; r += 2) {
                int d = (r&3) + 8*(r>>2) + 4*hi;
                *(uint32_t*)(sm + 32768 + q*256 + ((2*(wv*16 + d)) ^ ((q&7)<<4)))
                    = packbf(Ot[r]*ri, Ot[r+1]*ri);
            }
        }
    }
    __syncthreads();

    float win2[4][4];
    {
        f32x4 acc[4];
#pragma unroll
        for (int nt = 0; nt < 4; ++nt) acc[nt] = zero4();
#pragma unroll
        for (int ks = 0; ks < 4; ++ks) {
            int tok = fmt*16 + l15;
            bf16x8 afr = *(const bf16x8*)(sm + 32768 + tok*256 + ((ks*64 + l4*16) ^ ((tok&7)<<4)));
#pragma unroll
            for (int nt = 0; nt < 4; ++nt) {
                int n = fn0 + nt*16 + l15;
                bf16x8 bfr = *(const bf16x8*)(wprojT + n*128 + ks*32 + l4*8);
                acc[nt] = MFMA16(afr, bfr, acc[nt]);
            }
        }
#pragma unroll
        for (int nt = 0; nt < 4; ++nt) {
            float bp = b_proj[fn0 + nt*16 + l15];
#pragma unroll
            for (int r = 0; r < 4; ++r) {
                uint32_t w = winp[nt >> 1][r];
                float xr = uf((nt & 1) ? (w & 0xffff0000u) : (w << 16));
                win2[nt][r] = xr + acc[nt][r] + bp;
            }
        }
    }

    {
        float s[4], s2[4];
#pragma unroll
        for (int r = 0; r < 4; ++r) {
            s[r]  = win2[0][r] + win2[1][r] + win2[2][r] + win2[3][r];
            s2[r] = win2[0][r]*win2[0][r] + win2[1][r]*win2[1][r]
                  + win2[2][r]*win2[2][r] + win2[3][r]*win2[3][r];
#pragma unroll
            for (int m = 1; m < 16; m <<= 1) {
                s[r]  += __shfl_xor(s[r],  m, 64);
                s2[r] += __shfl_xor(s2[r], m, 64);
            }
        }
        float2* scr = (float2*)sm;
        if (l15 == 0) {
#pragma unroll
            for (int r = 0; r < 4; ++r) {
                int tok = fmt*16 + l4*4 + r;
                scr[tok*2 + (wv&1)] = make_float2(s[r], s2[r]);
            }
        }
        __syncthreads();
        float mean[4], rstd[4];
#pragma unroll
        for (int r = 0; r < 4; ++r) {
            int tok = fmt*16 + l4*4 + r;
            float2 p = scr[tok*2 + ((wv&1)^1)];
            float tot = s[r] + p.x, tot2 = s2[r] + p.y;
            float m = tot * 0.0078125f;
            mean[r] = m;
            rstd[r] = rsqrtf(tot2*0.0078125f - m*m + 1e-5f);
        }
#pragma unroll
        for (int nt = 0; nt < 4; ++nt) {
            int c = fn0 + nt*16 + l15;
            float gg = ln2_g[c], bb2 = ln2_b[c];
#pragma unroll
            for (int r = 0; r < 4; ++r) {
                int tok = fmt*16 + l4*4 + r;
                *(bf16*)(sm + 16384 + tok*256 + ((2*c) ^ ((tok&7)<<4)))
                    = (bf16)((win2[nt][r] - mean[r]) * rstd[r] * gg + bb2);
            }
        }
    }
    __syncthreads();

    {
        f32x4 acc2[4];
#pragma unroll
        for (int nt = 0; nt < 4; ++nt) acc2[nt] = zero4();
#pragma unroll
        for (int c4 = 0; c4 < 4; ++c4) {
            char* gbuf = (c4 & 1) ? (sm + 32768) : sm;
            {
                f32x4 a1[4];
#pragma unroll
                for (int nt = 0; nt < 4; ++nt) a1[nt] = zero4();
#pragma unroll
                for (int ks = 0; ks < 4; ++ks) {
                    int tok = fmt*16 + l15;
                    bf16x8 afr = *(const bf16x8*)(sm + 16384 + tok*256 + ((ks*64 + l4*16) ^ ((tok&7)<<4)));
#pragma unroll
                    for (int nt = 0; nt < 4; ++nt) {
                        int n = c4*128 + fn0 + nt*16 + l15;
                        bf16x8 bfr = *(const bf16x8*)(wfc1T + n*128 + ks*32 + l4*8);
                        a1[nt] = MFMA16(afr, bfr, a1[nt]);
                    }
                }
#pragma unroll
                for (int nt = 0; nt < 4; ++nt) {
                    int cl = fn0 + nt*16 + l15;
                    float b1 = b_fc1[c4*128 + cl];
#pragma unroll
                    for (int r = 0; r < 4; ++r) {
                        int tok = fmt*16 + l4*4 + r;
                        float u = a1[nt][r] + b1;
                        *(bf16*)(gbuf + tok*256 + ((2*cl) ^ ((tok&7)<<4))) = (bf16)gelu_f(u);
                    }
                }
            }
            __syncthreads();
#pragma unroll
            for (int ks = 0; ks < 4; ++ks) {
                int tok = fmt*16 + l15;
                bf16x8 afr = *(const bf16x8*)(gbuf + tok*256 + ((ks*64 + l4*16) ^ ((tok&7)<<4)));
#pragma unroll
                for (int nt = 0; nt < 4; ++nt) {
                    int n = fn0 + nt*16 + l15;
                    bf16x8 bfr = *(const bf16x8*)(wfc2T + n*512 + c4*128 + ks*32 + l4*8);
                    acc2[nt] = MFMA16(afr, bfr, acc2[nt]);
                }
            }
        }
#pragma unroll
        for (int nt = 0; nt < 4; ++nt) {
            float bf_ = b_fc2[fn0 + nt*16 + l15];
#pragma unroll
            for (int r = 0; r < 4; ++r) win2[nt][r] += acc2[nt][r] + bf_;
        }
    }
    __syncthreads();

#pragma unroll
    for (int nt = 0; nt < 4; ++nt)
#pragma unroll
        for (int r = 0; r < 4; ++r) {
            int tok = fmt*16 + l4*4 + r;
            int c   = fn0 + nt*16 + l15;
            *(float*)(sm + tok*512 + ((c*4) ^ ((tok&15)<<4))) = win2[nt][r];
        }
    __syncthreads();
#pragma unroll
    for (int it = 0; it < 4; ++it) {
        int idx = it*512 + tid;
        int c = idx >> 4, t2 = idx & 15;
        int row = t2 >> 1, col0 = (t2 & 1) * 4;
        f32x4 v;
#pragma unroll
        for (int e = 0; e < 4; ++e) {
            int t = row*8 + col0 + e;
            v[e] = *(const float*)(sm + t*512 + ((c*4) ^ ((t&15)<<4)));
        }
        *(f32x4*)(outw + (size_t)c*65536 + row*256 + col0) = v;
    }
}

extern "C" void kernel_launch(void* const* d_in, const int* in_sizes, int n_in,
                              void* d_out, int out_size, void* d_ws, size_t ws_size,
                              hipStream_t stream) {
    const float* x      = (const float*)d_in[0];
    const float* ln1_g  = (const float*)d_in[1];
    const float* ln1_b  = (const float*)d_in[2];
    const float* w_qkv  = (const float*)d_in[3];
    const float* b_qkv  = (const float*)d_in[4];
    const float* w_proj = (const float*)d_in[5];
    const float* b_proj = (const float*)d_in[6];
    const float* btab   = (const float*)d_in[7];
    const float* ln2_g  = (const float*)d_in[8];
    const float* ln2_b  = (const float*)d_in[9];
    const float* w_fc1  = (const float*)d_in[10];
    const float* b_fc1  = (const float*)d_in[11];
    const float* w_fc2  = (const float*)d_in[12];
    const float* b_fc2  = (const float*)d_in[13];
    const int*   relix  = (const int*)d_in[14];
    float* out = (float*)d_out;

    char* ws = (char*)d_ws;
    bf16*  wqkvT  = (bf16*)(ws);
    bf16*  wprojT = (bf16*)(ws + 98304);
    bf16*  wfc1T  = (bf16*)(ws + 131072);
    bf16*  wfc2T  = (bf16*)(ws + 262144);
    float* bN     = (float*)(ws + 393216);
    float* win2tm = (float*)(ws + 524288);

    prep_kernel<<<dim3(448), dim3(512), 0, stream>>>(
        w_qkv, w_proj, w_fc1, w_fc2, btab, relix,
        wqkvT, wprojT, wfc1T, wfc2T, bN);

    const size_t need = 524288ull + 134217728ull;
    if (ws_size >= need) {
        swin_attn<<<dim3(4096), dim3(512), 0, stream>>>(
            x, ln1_g, ln1_b, b_qkv, b_proj, wqkvT, wprojT, bN, win2tm);
        swin_mlp<<<dim3(4096), dim3(512), 0, stream>>>(
            win2tm, ln2_g, ln2_b, b_fc1, b_fc2, wfc1T, wfc2T, out);
    } else {
        swin_fused<<<dim3(4096), dim3(512), 0, stream>>>(
            x, ln1_g, ln1_b, b_qkv, b_proj, ln2_g, ln2_b, b_fc1, b_fc2,
            wqkvT, wprojT, wfc1T, wfc2T, bN, out);
    }
}